// Round 3
// baseline (1763.980 us; speedup 1.0000x reference)
//
#include <hip/hip_runtime.h>
#include <cstdint>
#include <cstddef>

typedef unsigned short u16;
typedef __attribute__((__ext_vector_type__(8))) __bf16 bf16x8;
typedef __attribute__((__ext_vector_type__(4))) float f32x4;
typedef __attribute__((__ext_vector_type__(8))) unsigned short u16x8;

#define DEVI __device__ __forceinline__

constexpr int Bb = 2, Ss = 1024, Dd = 1024, Hh = 16;
constexpr int Mm = Bb * Ss;       // 2048 token rows
constexpr int QKD = 128;          // padded q/k head dim (96 -> 128, zero pad)
constexpr float EPSF = 1.1920929e-07f;
constexpr float NEG = -1e30f;
constexpr float QSCALE = 0.10206207261596577f; // 1/sqrt(96)
constexpr float LOG1E4_16 = 9.210340371976184f / 16.f;

DEVI u16 f2b(float f) {
  union { float f; uint32_t u; } a; a.f = f;
  uint32_t r = a.u + 0x7FFFu + ((a.u >> 16) & 1u);
  return (u16)(r >> 16);
}
DEVI float b2f(u16 h) {
  union { uint32_t u; float f; } a; a.u = ((uint32_t)h) << 16; return a.f;
}

// ---------------- fp32 -> bf16 transposed weight conversion (K x N -> Npad x K)
__global__ void k_wcvt(const float* __restrict__ in, u16* __restrict__ out,
                       int K, int N, int Npad) {
  __shared__ float t[32][33];
  int bk = blockIdx.x * 32, bn = blockIdx.y * 32;
  int tx = threadIdx.x, ty = threadIdx.y;
  #pragma unroll
  for (int i = ty; i < 32; i += 8) {
    int n = bn + tx;
    t[i][tx] = (n < N) ? in[(size_t)(bk + i) * N + n] : 0.f;
  }
  __syncthreads();
  #pragma unroll
  for (int i = ty; i < 32; i += 8) {
    int n = bn + i;
    out[(size_t)n * K + bk + tx] = f2b(t[tx][i]);
  }
}

// ---------------- embedding gather
__global__ void k_embed(const int* __restrict__ tok, const float* __restrict__ emb,
                        float* __restrict__ h) {
  int m = blockIdx.x;
  int t = tok[m];
  const float4* src = (const float4*)(emb + (size_t)t * Dd);
  float4* dst = (float4*)(h + (size_t)m * Dd);
  dst[threadIdx.x] = src[threadIdx.x];
}

// ---------------- rmsnorm: f32 (stride inStride) -> bf16 (stride K)
__global__ void k_rms(const float* __restrict__ in, int inStride,
                      const float* __restrict__ w, u16* __restrict__ out, int K) {
  int m = blockIdx.x;
  const float* x = in + (size_t)m * inStride;
  float ss = 0.f;
  for (int i = threadIdx.x; i < K; i += 256) { float v = x[i]; ss += v * v; }
  #pragma unroll
  for (int off = 32; off; off >>= 1) ss += __shfl_xor(ss, off);
  __shared__ float red[4];
  if ((threadIdx.x & 63) == 0) red[threadIdx.x >> 6] = ss;
  __syncthreads();
  float r = rsqrtf((red[0] + red[1] + red[2] + red[3]) / (float)K + EPSF);
  for (int i = threadIdx.x; i < K; i += 256)
    out[(size_t)m * K + i] = f2b(x[i] * r * w[i]);
}

// ---------------- bias concat for fused down-proj (288 kv | pad | 384 q)
__global__ void k_biascat(const float* __restrict__ b1, const float* __restrict__ b2,
                          float* __restrict__ out) {
  int i = blockIdx.x * 256 + threadIdx.x;  // 0..767
  float v = 0.f;
  if (i < 288) v = b1[i];
  else if (i >= 384) v = b2[i - 384];
  out[i] = v;
}

// ---------------- build Q (rope on cols 64..95, *QSCALE, pad to 128)
__global__ void k_buildq(const float* __restrict__ qf, u16* __restrict__ Q) {
  int s = blockIdx.x, bh = blockIdx.y;
  int b = bh >> 4, h = bh & 15;
  int d = threadIdx.x;
  const float* row = qf + (size_t)(b * Ss + s) * (Hh * 96) + h * 96;
  float v = 0.f;
  if (d < 64) v = row[d];
  else if (d < 96) {
    int j = d - 64;
    int jj = j & 15;
    float theta = __expf(-(float)jj * LOG1E4_16);
    float ang = (float)s * theta;
    float sn, cs; __sincosf(ang, &sn, &cs);
    float x = row[64 + j];
    float o = row[64 + (j ^ 16)];
    v = x * cs + ((j < 16) ? -o : o) * sn;
  }
  Q[((size_t)bh * Ss + s) * QKD + d] = f2b(v * QSCALE);
}

// ---------------- build K (k from kv, roped k_rope from fused ckvq, bcast over heads)
__global__ void k_buildk(const float* __restrict__ kv, const float* __restrict__ ckvq,
                         u16* __restrict__ Kb) {
  int s = blockIdx.x, bh = blockIdx.y;
  int b = bh >> 4, h = bh & 15;
  int d = threadIdx.x;
  int m = b * Ss + s;
  float v = 0.f;
  if (d < 64) v = kv[(size_t)m * 2048 + h * 128 + d];
  else if (d < 96) {
    int j = d - 64;
    int jj = j & 15;
    float theta = __expf(-(float)jj * LOG1E4_16);
    float ang = (float)s * theta;
    float sn, cs; __sincosf(ang, &sn, &cs);
    const float* rr = ckvq + (size_t)m * 768 + 256;
    float x = rr[j];
    float o = rr[j ^ 16];
    v = x * cs + ((j < 16) ? -o : o) * sn;
  }
  Kb[((size_t)bh * Ss + s) * QKD + d] = f2b(v);
}

// ---------------- build V^T (per head: [64 rows used of 128][1024]), bf16
__global__ void k_buildvt(const float* __restrict__ kv, u16* __restrict__ Vt) {
  __shared__ float t[32][33];
  int bh = blockIdx.x, s0 = blockIdx.y * 32, d0 = blockIdx.z * 32;
  int b = bh >> 4, h = bh & 15;
  int tx = threadIdx.x, ty = threadIdx.y;
  #pragma unroll
  for (int i = ty; i < 32; i += 8) {
    int s = s0 + i, d = d0 + tx;
    t[i][tx] = kv[(size_t)(b * Ss + s) * 2048 + h * 128 + 64 + d];
  }
  __syncthreads();
  #pragma unroll
  for (int i = ty; i < 32; i += 8) {
    int d = d0 + i, s = s0 + tx;
    Vt[((size_t)bh * 128 + d) * Ss + s] = f2b(t[tx][i]);
  }
}

// ---------------- in-place row softmax, causal by index (upper region may be garbage)
__global__ void k_softmax(u16* __restrict__ sc) {
  int gr = blockIdx.x * 4 + (threadIdx.x >> 6);
  int row = gr & 1023;               // position within sequence
  int lane = threadIdx.x & 63;
  u16* p = sc + (size_t)gr * 1024;
  u16x8 h0 = *(const u16x8*)(p + lane * 8);
  u16x8 h1 = *(const u16x8*)(p + 512 + lane * 8);
  float v[16];
  #pragma unroll
  for (int i = 0; i < 8; i++) {
    int c0 = lane * 8 + i, c1 = 512 + lane * 8 + i;
    v[i]     = (c0 <= row) ? b2f(h0[i]) : NEG;
    v[8 + i] = (c1 <= row) ? b2f(h1[i]) : NEG;
  }
  float mx = v[0];
  #pragma unroll
  for (int i = 1; i < 16; i++) mx = fmaxf(mx, v[i]);
  #pragma unroll
  for (int off = 32; off; off >>= 1) mx = fmaxf(mx, __shfl_xor(mx, off));
  float sum = 0.f;
  #pragma unroll
  for (int i = 0; i < 16; i++) { v[i] = __expf(v[i] - mx); sum += v[i]; }
  #pragma unroll
  for (int off = 32; off; off >>= 1) sum += __shfl_xor(sum, off);
  float inv = 1.f / sum;
  #pragma unroll
  for (int i = 0; i < 8; i++) { h0[i] = f2b(v[i] * inv); h1[i] = f2b(v[8 + i] * inv); }
  *(u16x8*)(p + lane * 8) = h0;
  *(u16x8*)(p + 512 + lane * 8) = h1;
}

#define GAS __attribute__((address_space(1)))
#define LAS __attribute__((address_space(3)))
DEVI void gll16(const void* g, void* l) {
  __builtin_amdgcn_global_load_lds((GAS const void*)g, (LAS void*)l, 16, 0, 0);
}

// ---------------- 256x256x64 8-phase bf16 GEMM (T2+T3+T4+T5), f32 out + bias
// A: MxK row-major bf16 (M = 8*256 via grid), Bt: N x K row-major bf16.
// Grid: flat, (M/256)*(N/256) blocks, M/256 must be 8. 512 threads (8 waves 2Mx4N).
// LDS: 2 dbuf x (A[256][64] + B[256][64]) bf16, stage-unit permuted rows:
//   A slot = mh*128 + H*64 + r6   (row = H*128 + mh*64 + r6)
//   B slot = nh*128 + w2*32 + r5  (row = w2*64  + nh*32 + r5)
// so unit consumption is staggered: Au0@ph0-1, Bu0@ph0/2, Bu1@ph1/3, Au1@ph2-3.
// K-group XOR swizzle (involution): global group c stored at LDS group c^(row&7).
__global__ __launch_bounds__(512, 2) void k_gemm256(
    const u16* __restrict__ A, const u16* __restrict__ Bt,
    const float* __restrict__ bias, float* __restrict__ C,
    int N, int K) {
  __shared__ u16 lA[2][16384];
  __shared__ u16 lB[2][16384];
  const int tid = threadIdx.x;
  const int nwg = gridDim.x;
  const int f = blockIdx.x;
  const int t = (f & 7) * (nwg >> 3) + (f >> 3);   // xcd swizzle (nwg % 8 == 0)
  const long m0 = (long)(t & 7) * 256;
  const long n0 = (long)(t >> 3) * 256;
  const int lane = tid & 63, wid = tid >> 6;
  const int H = wid >> 2, w2 = wid & 3;
  const int fr = lane & 15, l4 = lane >> 4;
  const int NT = K >> 6;

  auto stageA = [&](int buf, int kk, int mh) {
    #pragma unroll
    for (int g = 0; g < 2; ++g) {
      int r6 = tid >> 3;
      int row = g * 128 + mh * 64 + r6;
      int slot = mh * 128 + g * 64 + r6;
      const u16* src = A + (m0 + row) * (long)K + kk + (((tid & 7) ^ (r6 & 7)) << 3);
      gll16(src, &lA[buf][slot * 64 + (tid & 7) * 8]);
    }
  };
  auto stageB = [&](int buf, int kk, int nh) {
    #pragma unroll
    for (int g = 0; g < 2; ++g) {
      int s127 = g * 64 + (tid >> 3);
      int row = (s127 >> 5) * 64 + nh * 32 + (s127 & 31);
      int slot = nh * 128 + s127;
      const u16* src = Bt + (n0 + row) * (long)K + kk + (((tid & 7) ^ (s127 & 7)) << 3);
      gll16(src, &lB[buf][slot * 64 + (tid & 7) * 8]);
    }
  };

  f32x4 acc[8][4] = {};

  // prologue: tile 0 -> buf0, in consumption order Au0, Bu0, Bu1, Au1
  stageA(0, 0, 0); stageB(0, 0, 0); stageB(0, 0, 1); stageA(0, 0, 1);
  asm volatile("s_waitcnt vmcnt(4)" ::: "memory");   // Au0,Bu0 landed
  __builtin_amdgcn_s_barrier();
  asm volatile("" ::: "memory");

  for (int j = 0; j < NT; ++j) {
    const int cur = j & 1;
    const int kk1 = (j + 1) << 6;
    const bool more = (j + 1 < NT);
    #pragma unroll
    for (int q = 0; q < 4; ++q) {
      const int mh = q >> 1, nh = q & 1;
      bf16x8 af[4][2], bfp[2][2];
      #pragma unroll
      for (int i = 0; i < 4; ++i)
        #pragma unroll
        for (int ks = 0; ks < 2; ++ks) {
          int slot = mh * 128 + H * 64 + i * 16 + fr;
          int c = (ks * 4 + l4) ^ (fr & 7);
          af[i][ks] = *(const bf16x8*)&lA[cur][slot * 64 + c * 8];
        }
      #pragma unroll
      for (int nl = 0; nl < 2; ++nl)
        #pragma unroll
        for (int ks = 0; ks < 2; ++ks) {
          int slot = nh * 128 + w2 * 32 + nl * 16 + fr;
          int c = (ks * 4 + l4) ^ (fr & 7);
          bfp[nl][ks] = *(const bf16x8*)&lB[cur][slot * 64 + c * 8];
        }
      if (more) {  // stage tile j+1 unit q into buf[cur^1], 4 phases ahead of use
        if (q == 0) stageA(cur ^ 1, kk1, 0);
        else if (q == 1) stageB(cur ^ 1, kk1, 0);
        else if (q == 2) stageB(cur ^ 1, kk1, 1);
        else stageA(cur ^ 1, kk1, 1);
      }
      asm volatile("" ::: "memory");
      __builtin_amdgcn_s_barrier();
      asm volatile("" ::: "memory");
      __builtin_amdgcn_s_setprio(1);
      #pragma unroll
      for (int i = 0; i < 4; ++i)
        #pragma unroll
        for (int nl = 0; nl < 2; ++nl) {
          acc[mh * 4 + i][nh * 2 + nl] = __builtin_amdgcn_mfma_f32_16x16x32_bf16(
              af[i][0], bfp[nl][0], acc[mh * 4 + i][nh * 2 + nl], 0, 0, 0);
          acc[mh * 4 + i][nh * 2 + nl] = __builtin_amdgcn_mfma_f32_16x16x32_bf16(
              af[i][1], bfp[nl][1], acc[mh * 4 + i][nh * 2 + nl], 0, 0, 0);
        }
      __builtin_amdgcn_s_setprio(0);
      // counted vmem waits: each unit must land 1 phase before its first read.
      if (more) {
        if (q != 2) asm volatile("s_waitcnt vmcnt(4)" ::: "memory");
      } else {
        if (q == 0) asm volatile("s_waitcnt vmcnt(2)" ::: "memory");
        else if (q == 1) asm volatile("s_waitcnt vmcnt(0)" ::: "memory");
      }
      __builtin_amdgcn_s_barrier();
      asm volatile("" ::: "memory");
    }
  }

  const long r0 = m0 + H * 128 + l4 * 4;
  const long c0 = n0 + w2 * 64 + fr;
  #pragma unroll
  for (int ni = 0; ni < 4; ++ni) {
    long col = c0 + ni * 16;
    if (col < N) {
      float bs = bias[col];
      #pragma unroll
      for (int mi = 0; mi < 8; ++mi)
        #pragma unroll
        for (int r = 0; r < 4; ++r)
          C[(r0 + mi * 16 + r) * (long)N + col] = acc[mi][ni][r] + bs;
    }
  }
}

// ---------------- bf16 MFMA GEMM 128x128 (m97 structure), modes as before
template <int MODE, int BN, bool SWZ>
__global__ __launch_bounds__(256) void k_gemm(
    const u16* __restrict__ A, const u16* __restrict__ Bt,
    const float* __restrict__ bias, void* __restrict__ C,
    int N, int K, long sA, long sB, long sC) {
  __shared__ u16 lA[128 * 32];
  __shared__ u16 lB[BN * 32];
  const int tid = threadIdx.x;
  const int bz = blockIdx.z;

  int bx, by;
  if (MODE == 2) {
    int t = blockIdx.x;
    bx = (int)((sqrtf(8.f * t + 1.f) - 1.f) * 0.5f);
    while ((bx + 1) * (bx + 2) / 2 <= t) ++bx;
    while (bx * (bx + 1) / 2 > t) --bx;
    by = t - bx * (bx + 1) / 2;
  } else if (SWZ) {
    int gx = gridDim.x;
    int nwg = gx * gridDim.y;
    int f = blockIdx.y * gx + blockIdx.x;
    int f2 = (f & 7) * (nwg >> 3) + (f >> 3);
    bx = f2 % gx; by = f2 / gx;
  } else {
    bx = blockIdx.x; by = blockIdx.y;
  }
  const long m0 = (long)bx * 128, n0 = (long)by * BN;

  const u16* Az = A + (size_t)bz * sA;
  const u16* Bz = Bt + (size_t)bz * sB;
  const int srow = tid >> 2;
  const int scol = (tid & 3) << 3;
  const u16* a0 = Az + (m0 + srow) * (long)K + scol;
  const u16* b0 = Bz + (n0 + srow) * (long)K + scol;
  const long rstep = 64L * K;

  const int lane = tid & 63, wid = tid >> 6;
  constexpr int WR = (BN == 128) ? 64 : 32;
  constexpr int MI = WR / 16;
  const int wm = (BN == 128) ? (wid >> 1) * 64 : wid * 32;
  const int wn = (BN == 128) ? (wid & 1) * 64 : 0;
  const int fr = lane & 15, kg = (lane >> 4) * 8;

  f32x4 acc[MI][4] = {};

  for (int kk = 0; kk < K; kk += 32) {
    gll16(a0 + kk, lA + tid * 8);
    gll16(a0 + rstep + kk, lA + 2048 + tid * 8);
    gll16(b0 + kk, lB + tid * 8);
    if (BN == 128) gll16(b0 + rstep + kk, lB + 2048 + tid * 8);
    __syncthreads();
    bf16x8 af[MI], bfr[4];
    #pragma unroll
    for (int i = 0; i < MI; i++) af[i] = *(const bf16x8*)&lA[(wm + i * 16 + fr) * 32 + kg];
    #pragma unroll
    for (int j = 0; j < 4; j++) bfr[j] = *(const bf16x8*)&lB[(wn + j * 16 + fr) * 32 + kg];
    #pragma unroll
    for (int i = 0; i < MI; i++)
      #pragma unroll
      for (int j = 0; j < 4; j++)
        acc[i][j] = __builtin_amdgcn_mfma_f32_16x16x32_bf16(af[i], bfr[j], acc[i][j], 0, 0, 0);
    __syncthreads();
  }

  const int rb = wm + ((lane >> 4) << 2);
  const int cb = wn + (lane & 15);
  #pragma unroll
  for (int j = 0; j < 4; j++) {
    long gcol = n0 + cb + j * 16;
    float bs = 0.f;
    if ((MODE == 0 || MODE == 1) && gcol < N) bs = bias[gcol];
    #pragma unroll
    for (int i = 0; i < MI; i++) {
      #pragma unroll
      for (int r = 0; r < 4; r++) {
        long grow = m0 + rb + i * 16 + r;
        float val = acc[i][j][r];
        if (MODE == 0) {
          if (gcol < N) ((float*)C)[grow * N + gcol] = val + bs;
        } else if (MODE == 1) {
          if (gcol < N) { float* p = (float*)C + grow * N + gcol; *p += val + bs; }
        } else if (MODE == 2) {
          u16* out = (u16*)C + (size_t)bz * sC;
          out[grow * 1024 + gcol] = f2b((gcol <= grow) ? val : NEG);
        } else {
          int b = bz >> 4, h = bz & 15;
          ((u16*)C)[((size_t)(b * Ss) + grow) * Dd + h * 64 + gcol] = f2b(val);
        }
      }
    }
  }
}

// ---------------- silu gate: uv (2048 x 5632 f32) -> gated bf16 (2048 x 2816)
__global__ void k_silu(const float* __restrict__ uv, u16* __restrict__ g) {
  int n = blockIdx.x * 256 + threadIdx.x;
  int m = blockIdx.y;
  float u = uv[(size_t)m * 5632 + n];
  float x = uv[(size_t)m * 5632 + 2816 + n];
  float sg = 1.f / (1.f + __expf(-x));
  g[(size_t)m * 2816 + n] = f2b(u * x * sg);
}

extern "C" void kernel_launch(void* const* d_in, const int* in_sizes, int n_in,
                              void* d_out, int out_size, void* d_ws, size_t ws_size,
                              hipStream_t stream) {
  (void)in_sizes; (void)n_in; (void)out_size; (void)ws_size;
  const int*   tokens    = (const int*)  d_in[0];
  const float* embed     = (const float*)d_in[1];
  const float* w_kv_down = (const float*)d_in[2];
  const float* b_kv_down = (const float*)d_in[3];
  const float* w_q_down  = (const float*)d_in[4];
  const float* b_q_down  = (const float*)d_in[5];
  const float* w_kv_up   = (const float*)d_in[6];
  const float* b_kv_up   = (const float*)d_in[7];
  const float* w_q_up    = (const float*)d_in[8];
  const float* b_q_up    = (const float*)d_in[9];
  const float* w_o       = (const float*)d_in[10];
  const float* b_o       = (const float*)d_in[11];
  const float* kv_norm_w = (const float*)d_in[12];
  const float* q_norm_w  = (const float*)d_in[13];
  const float* norm1_w   = (const float*)d_in[14];
  const float* norm2_w   = (const float*)d_in[15];
  const float* w_in      = (const float*)d_in[16];
  const float* b_in      = (const float*)d_in[17];
  const float* w_out     = (const float*)d_in[18];
  const float* b_out     = (const float*)d_in[19];
  const float* norm_f_w  = (const float*)d_in[20];
  const float* w_head    = (const float*)d_in[21];
  const float* b_head    = (const float*)d_in[22];

  char* base = (char*)d_ws;
  size_t off = 0;
  auto alloc = [&](size_t bytes) -> void* {
    void* p = base + off;
    off += (bytes + 255) & ~(size_t)255;
    return p;
  };
  u16* warena = (u16*)alloc((size_t)32000 * 1024 * 2);
  u16* wT_dq    = warena;                        // 768 x 1024
  u16* wT_kvup  = wT_dq   + 768 * 1024;          // 2048 x 256
  u16* wT_qup   = wT_kvup + 2048 * 256;          // 1536 x 384
  u16* wT_o     = wT_qup  + 1536 * 384;          // 1024 x 1024
  u16* wT_in    = wT_o    + 1024 * 1024;         // 5632 x 1024
  u16* wT_out   = wT_in   + 5632 * 1024;         // 1024 x 2816

  float* h     = (float*)alloc((size_t)Mm * 1024 * 4);
  u16*   xn    = (u16*)  alloc((size_t)Mm * 1024 * 2);
  float* ckvq  = (float*)alloc((size_t)Mm * 768 * 4);
  float* bdq   = (float*)alloc(768 * 4);
  u16*   ckvn  = (u16*)  alloc((size_t)Mm * 256 * 2);
  float* kv    = (float*)alloc((size_t)Mm * 2048 * 4);
  u16*   qdn   = (u16*)  alloc((size_t)Mm * 384 * 2);
  float* qf    = (float*)alloc((size_t)Mm * 1536 * 4);
  u16*   Qb    = (u16*)  alloc((size_t)32 * 1024 * QKD * 2);
  u16*   Kb    = (u16*)  alloc((size_t)32 * 1024 * QKD * 2);
  u16*   Vt    = (u16*)  alloc((size_t)32 * 128 * 1024 * 2);
  void* bigbuf = alloc((size_t)32 * 1024 * 1024 * 2);
  u16*   sc    = (u16*)bigbuf;
  float* uvb   = (float*)bigbuf;
  u16*   attn  = (u16*)  alloc((size_t)Mm * 1024 * 2);
  u16*   gate  = (u16*)  alloc((size_t)Mm * 2816 * 2);

  dim3 tb(32, 8);
  auto cvt = [&](const float* src, u16* dst, int K, int N, int Npad) {
    dim3 gg(K / 32, Npad / 32);
    k_wcvt<<<gg, tb, 0, stream>>>(src, dst, K, N, Npad);
  };

  k_embed<<<Mm, 256, 0, stream>>>(tokens, embed, h);

  for (int l = 0; l < 4; l++) {
    cvt(w_kv_down + (size_t)l * 1024 * 288,  wT_dq,            1024, 288, 384);
    cvt(w_q_down  + (size_t)l * 1024 * 384,  wT_dq + 384*1024, 1024, 384, 384);
    cvt(w_kv_up   + (size_t)l * 256 * 2048,  wT_kvup,          256, 2048, 2048);
    cvt(w_q_up    + (size_t)l * 384 * 1536,  wT_qup,           384, 1536, 1536);
    cvt(w_o       + (size_t)l * 1024 * 1024, wT_o,             1024, 1024, 1024);
    cvt(w_in      + (size_t)l * 1024 * 5632, wT_in,            1024, 5632, 5632);
    cvt(w_out     + (size_t)l * 2816 * 1024, wT_out,           2816, 1024, 1024);
    k_biascat<<<3, 256, 0, stream>>>(b_kv_down + l * 288, b_q_down + l * 384, bdq);

    k_rms<<<Mm, 256, 0, stream>>>(h, 1024, norm1_w + l * 1024, xn, 1024);
    k_gemm<0, 128, true><<<dim3(16, 6), 256, 0, stream>>>(xn, wT_dq, bdq,
                                                          ckvq, 768, 1024, 0, 0, 0);
    k_rms<<<Mm, 256, 0, stream>>>(ckvq, 768, kv_norm_w + l * 256, ckvn, 256);
    k_gemm<0, 128, true><<<dim3(16, 16), 256, 0, stream>>>(ckvn, wT_kvup, b_kv_up + l * 2048,
                                                           kv, 2048, 256, 0, 0, 0);
    k_rms<<<Mm, 256, 0, stream>>>(ckvq + 384, 768, q_norm_w + l * 384, qdn, 384);
    k_gemm<0, 128, true><<<dim3(16, 12), 256, 0, stream>>>(qdn, wT_qup, b_q_up + l * 1536,
                                                           qf, 1536, 384, 0, 0, 0);
    k_buildq<<<dim3(Ss, 32), 128, 0, stream>>>(qf, Qb);
    k_buildk<<<dim3(Ss, 32), 128, 0, stream>>>(kv, ckvq, Kb);
    k_buildvt<<<dim3(32, 32, 2), tb, 0, stream>>>(kv, Vt);
    k_gemm<2, 128, false><<<dim3(36, 1, 32), 256, 0, stream>>>(Qb, Kb, nullptr, sc,
                                                               1024, 128, 1024L * 128,
                                                               1024L * 128, 1024L * 1024);
    k_softmax<<<(32 * 1024) / 4, 256, 0, stream>>>(sc);
    k_gemm<3, 64, false><<<dim3(8, 1, 32), 256, 0, stream>>>(sc, Vt, nullptr, attn,
                                                             64, 1024, 1024L * 1024,
                                                             128L * 1024, 0);
    k_gemm<1, 128, true><<<dim3(16, 8), 256, 0, stream>>>(attn, wT_o, b_o + l * 1024,
                                                          h, 1024, 1024, 0, 0, 0);
    k_rms<<<Mm, 256, 0, stream>>>(h, 1024, norm2_w + l * 1024, xn, 1024);
    // w_in via 256^2 8-phase kernel: grid = (2048/256)*(5632/256) = 176
    k_gemm256<<<176, 512, 0, stream>>>(xn, wT_in, b_in + l * 5632, uvb, 5632, 1024);
    k_silu<<<dim3(11, Mm), 256, 0, stream>>>(uvb, gate);
    k_gemm<1, 128, true><<<dim3(16, 8), 256, 0, stream>>>(gate, wT_out, b_out + l * 1024,
                                                          h, 1024, 2816, 0, 0, 0);
  }

  k_rms<<<Mm, 256, 0, stream>>>(h, 1024, norm_f_w, xn, 1024);
  cvt(w_head, warena, 1024, 32000, 32000);
  // head via 256^2 8-phase kernel: grid = (2048/256)*(32000/256) = 1000
  k_gemm256<<<1000, 512, 0, stream>>>(xn, warena, b_head, (float*)d_out, 32000, 1024);
}

// Round 4
// 1462.241 us; speedup vs baseline: 1.2064x; 1.2064x over previous
//
#include <hip/hip_runtime.h>
#include <cstdint>
#include <cstddef>

typedef unsigned short u16;
typedef __attribute__((__ext_vector_type__(8))) __bf16 bf16x8;
typedef __attribute__((__ext_vector_type__(4))) float f32x4;
typedef __attribute__((__ext_vector_type__(8))) unsigned short u16x8;

#define DEVI __device__ __forceinline__

constexpr int Bb = 2, Ss = 1024, Dd = 1024, Hh = 16;
constexpr int Mm = Bb * Ss;       // 2048 token rows
constexpr int QKD = 128;          // padded q/k head dim (96 -> 128, zero pad)
constexpr float EPSF = 1.1920929e-07f;
constexpr float NEG = -1e30f;
constexpr float QSCALE = 0.10206207261596577f; // 1/sqrt(96)
constexpr float LOG1E4_16 = 9.210340371976184f / 16.f;

DEVI u16 f2b(float f) {
  union { float f; uint32_t u; } a; a.f = f;
  uint32_t r = a.u + 0x7FFFu + ((a.u >> 16) & 1u);
  return (u16)(r >> 16);
}
DEVI float b2f(u16 h) {
  union { uint32_t u; float f; } a; a.u = ((uint32_t)h) << 16; return a.f;
}

// ---------------- fp32 -> bf16 transposed weight conversion (K x N -> Npad x K)
__global__ void k_wcvt(const float* __restrict__ in, u16* __restrict__ out,
                       int K, int N, int Npad) {
  __shared__ float t[32][33];
  int bk = blockIdx.x * 32, bn = blockIdx.y * 32;
  int tx = threadIdx.x, ty = threadIdx.y;
  #pragma unroll
  for (int i = ty; i < 32; i += 8) {
    int n = bn + tx;
    t[i][tx] = (n < N) ? in[(size_t)(bk + i) * N + n] : 0.f;
  }
  __syncthreads();
  #pragma unroll
  for (int i = ty; i < 32; i += 8) {
    int n = bn + i;
    out[(size_t)n * K + bk + tx] = f2b(t[tx][i]);
  }
}

// ---------------- embedding gather
__global__ void k_embed(const int* __restrict__ tok, const float* __restrict__ emb,
                        float* __restrict__ h) {
  int m = blockIdx.x;
  int t = tok[m];
  const float4* src = (const float4*)(emb + (size_t)t * Dd);
  float4* dst = (float4*)(h + (size_t)m * Dd);
  dst[threadIdx.x] = src[threadIdx.x];
}

// ---------------- rmsnorm: f32 (stride inStride) -> bf16 (stride K)
__global__ void k_rms(const float* __restrict__ in, int inStride,
                      const float* __restrict__ w, u16* __restrict__ out, int K) {
  int m = blockIdx.x;
  const float* x = in + (size_t)m * inStride;
  float ss = 0.f;
  for (int i = threadIdx.x; i < K; i += 256) { float v = x[i]; ss += v * v; }
  #pragma unroll
  for (int off = 32; off; off >>= 1) ss += __shfl_xor(ss, off);
  __shared__ float red[4];
  if ((threadIdx.x & 63) == 0) red[threadIdx.x >> 6] = ss;
  __syncthreads();
  float r = rsqrtf((red[0] + red[1] + red[2] + red[3]) / (float)K + EPSF);
  for (int i = threadIdx.x; i < K; i += 256)
    out[(size_t)m * K + i] = f2b(x[i] * r * w[i]);
}

// ---------------- bias concat for fused down-proj (288 kv | pad | 384 q)
__global__ void k_biascat(const float* __restrict__ b1, const float* __restrict__ b2,
                          float* __restrict__ out) {
  int i = blockIdx.x * 256 + threadIdx.x;  // 0..767
  float v = 0.f;
  if (i < 288) v = b1[i];
  else if (i >= 384) v = b2[i - 384];
  out[i] = v;
}

// ---------------- build Q (rope on cols 64..95, *QSCALE, pad to 128)
__global__ void k_buildq(const float* __restrict__ qf, u16* __restrict__ Q) {
  int s = blockIdx.x, bh = blockIdx.y;
  int b = bh >> 4, h = bh & 15;
  int d = threadIdx.x;
  const float* row = qf + (size_t)(b * Ss + s) * (Hh * 96) + h * 96;
  float v = 0.f;
  if (d < 64) v = row[d];
  else if (d < 96) {
    int j = d - 64;
    int jj = j & 15;
    float theta = __expf(-(float)jj * LOG1E4_16);
    float ang = (float)s * theta;
    float sn, cs; __sincosf(ang, &sn, &cs);
    float x = row[64 + j];
    float o = row[64 + (j ^ 16)];
    v = x * cs + ((j < 16) ? -o : o) * sn;
  }
  Q[((size_t)bh * Ss + s) * QKD + d] = f2b(v * QSCALE);
}

// ---------------- build K (k from kv, roped k_rope from fused ckvq, bcast over heads)
__global__ void k_buildk(const float* __restrict__ kv, const float* __restrict__ ckvq,
                         u16* __restrict__ Kb) {
  int s = blockIdx.x, bh = blockIdx.y;
  int b = bh >> 4, h = bh & 15;
  int d = threadIdx.x;
  int m = b * Ss + s;
  float v = 0.f;
  if (d < 64) v = kv[(size_t)m * 2048 + h * 128 + d];
  else if (d < 96) {
    int j = d - 64;
    int jj = j & 15;
    float theta = __expf(-(float)jj * LOG1E4_16);
    float ang = (float)s * theta;
    float sn, cs; __sincosf(ang, &sn, &cs);
    const float* rr = ckvq + (size_t)m * 768 + 256;
    float x = rr[j];
    float o = rr[j ^ 16];
    v = x * cs + ((j < 16) ? -o : o) * sn;
  }
  Kb[((size_t)bh * Ss + s) * QKD + d] = f2b(v);
}

// ---------------- build V^T (per head: [64][1024]), bf16
__global__ void k_buildvt(const float* __restrict__ kv, u16* __restrict__ Vt) {
  __shared__ float t[32][33];
  int bh = blockIdx.x, s0 = blockIdx.y * 32, d0 = blockIdx.z * 32;
  int b = bh >> 4, h = bh & 15;
  int tx = threadIdx.x, ty = threadIdx.y;
  #pragma unroll
  for (int i = ty; i < 32; i += 8) {
    int s = s0 + i, d = d0 + tx;
    t[i][tx] = kv[(size_t)(b * Ss + s) * 2048 + h * 128 + 64 + d];
  }
  __syncthreads();
  #pragma unroll
  for (int i = ty; i < 32; i += 8) {
    int d = d0 + i, s = s0 + tx;
    Vt[((size_t)bh * 64 + d) * Ss + s] = f2b(t[tx][i]);
  }
}

#define GAS __attribute__((address_space(1)))
#define LAS __attribute__((address_space(3)))
DEVI void gll16(const void* g, void* l) {
  __builtin_amdgcn_global_load_lds((GAS const void*)g, (LAS void*)l, 16, 0, 0);
}

// ---------------- fused flash attention (causal), bf16 in/out
// grid (8 pairs, 32 bh), 256 thr (4 waves). Block handles q-tiles {p, 15-p}
// of 64 rows each -> 17 K-steps total per block (balanced).
// Swapped QK^T: ST = mfma(K_frag, Q_frag) so softmax row q == lane&15.
// K/V tiles staged via global_load_lds with XOR-16B-chunk swizzle (T2).
__global__ __launch_bounds__(256) void k_flash(
    const u16* __restrict__ Qg, const u16* __restrict__ Kg,
    const u16* __restrict__ Vtg, u16* __restrict__ attn) {
  __shared__ u16 lK[64 * 128];
  __shared__ u16 lV[64 * 64];
  __shared__ u16 lP[4][16 * 64];
  const int tid = threadIdx.x;
  const int pair = blockIdx.x, bh = blockIdx.y;
  const int b = bh >> 4, h = bh & 15;
  const int lane = tid & 63, w = tid >> 6;
  const int g = lane >> 4, fr = lane & 15;
  const u16* Qh = Qg + (size_t)bh * Ss * QKD;
  const u16* Kh = Kg + (size_t)bh * Ss * QKD;
  const u16* Vh = Vtg + (size_t)bh * 64 * Ss;

  for (int pass = 0; pass < 2; ++pass) {
    const int qt = pass ? (15 - pair) : pair;
    const int q0 = qt * 64;
    // Q frags: af[k4] = Q[q0 + w*16 + fr][k4*32 + g*8 .. +8]
    bf16x8 af[4];
    const u16* qrow = Qh + (size_t)(q0 + w * 16 + fr) * QKD + g * 8;
    #pragma unroll
    for (int k4 = 0; k4 < 4; ++k4) af[k4] = *(const bf16x8*)(qrow + k4 * 32);

    f32x4 acc_o[4] = {};
    float mrow = NEG, lrow = 0.f;

    for (int kt = 0; kt <= qt; ++kt) {
      // stage K tile [64][128] and V tile [64][64], swizzled source chunks
      {
        int r = tid >> 4, c = tid & 15;
        #pragma unroll
        for (int gg = 0; gg < 4; ++gg) {
          int row = gg * 16 + r;
          const u16* src = Kh + (size_t)(kt * 64 + row) * QKD + ((c ^ (row & 7)) * 8);
          gll16(src, (u16*)lK + gg * 2048 + tid * 8);
        }
        int r2 = tid >> 3, c2 = tid & 7;
        #pragma unroll
        for (int gg = 0; gg < 2; ++gg) {
          int d = gg * 32 + r2;
          const u16* src = Vh + (size_t)d * Ss + kt * 64 + ((c2 ^ (d & 7)) * 8);
          gll16(src, (u16*)lV + gg * 2048 + tid * 8);
        }
      }
      asm volatile("s_waitcnt vmcnt(0)" ::: "memory");
      __builtin_amdgcn_s_barrier();
      asm volatile("" ::: "memory");

      // ST tiles: accs[j] covers k-rows [j*16,j*16+16) x q-cols [w*16,w*16+16)
      f32x4 accs[4] = {};
      #pragma unroll
      for (int j = 0; j < 4; ++j) {
        #pragma unroll
        for (int k4 = 0; k4 < 4; ++k4) {
          int row = j * 16 + fr;
          int ch = (k4 * 4 + g) ^ (row & 7);
          bf16x8 kf = *(const bf16x8*)&lK[row * 128 + ch * 8];
          accs[j] = __builtin_amdgcn_mfma_f32_16x16x32_bf16(kf, af[k4], accs[j], 0, 0, 0);
        }
      }

      // mask + online softmax (row q = fr; lane holds k = j*16 + 4g + r)
      float p[16];
      float tmax = NEG;
      #pragma unroll
      for (int j = 0; j < 4; ++j)
        #pragma unroll
        for (int r = 0; r < 4; ++r) {
          float s = accs[j][r];
          int kloc = j * 16 + 4 * g + r;
          bool valid = (kt < qt) || (kloc <= w * 16 + fr);
          s = valid ? s : NEG;
          p[j * 4 + r] = s;
          tmax = fmaxf(tmax, s);
        }
      tmax = fmaxf(tmax, __shfl_xor(tmax, 16));
      tmax = fmaxf(tmax, __shfl_xor(tmax, 32));
      float mnew = fmaxf(mrow, tmax);
      float scale = __expf(mrow - mnew);
      float tsum = 0.f;
      #pragma unroll
      for (int i = 0; i < 16; ++i) { p[i] = __expf(p[i] - mnew); tsum += p[i]; }
      tsum += __shfl_xor(tsum, 16);
      tsum += __shfl_xor(tsum, 32);
      lrow = lrow * scale + tsum;
      mrow = mnew;

      // write P (bf16-pair packed) to per-wave LDS, swizzled
      #pragma unroll
      for (int j = 0; j < 4; ++j)
        #pragma unroll
        for (int t = 0; t < 2; ++t) {
          uint32_t u = (uint32_t)f2b(p[j * 4 + 2 * t]) |
                       ((uint32_t)f2b(p[j * 4 + 2 * t + 1]) << 16);
          int kp = 8 * j + 2 * g + t;
          int ch = kp >> 2, wi = kp & 3;
          ((uint32_t*)lP[w])[fr * 32 + ((ch ^ (fr & 7)) << 2) + wi] = u;
        }

      // rescale acc_o rows (q = 4g + r) by per-row scale
      float sc_q[4];
      #pragma unroll
      for (int r = 0; r < 4; ++r) sc_q[r] = __shfl(scale, 4 * g + r);
      #pragma unroll
      for (int j2 = 0; j2 < 4; ++j2)
        #pragma unroll
        for (int r = 0; r < 4; ++r) acc_o[j2][r] *= sc_q[r];

      // PV: out[q][d] += P[q][k] * Vt[d][k]
      #pragma unroll
      for (int ksub = 0; ksub < 2; ++ksub) {
        int chp = (4 * ksub + g) ^ (fr & 7);
        bf16x8 pa = *(const bf16x8*)&((const u16*)lP[w])[fr * 64 + chp * 8];
        #pragma unroll
        for (int j2 = 0; j2 < 4; ++j2) {
          int d = j2 * 16 + fr;
          int chv = (ksub * 4 + g) ^ (d & 7);
          bf16x8 vf = *(const bf16x8*)&lV[d * 64 + chv * 8];
          acc_o[j2] = __builtin_amdgcn_mfma_f32_16x16x32_bf16(pa, vf, acc_o[j2], 0, 0, 0);
        }
      }
      asm volatile("" ::: "memory");
      __builtin_amdgcn_s_barrier();
      asm volatile("" ::: "memory");
    }

    // finalize: divide by l (per q-row), store to (B,S,H*64)
    float li[4];
    #pragma unroll
    for (int r = 0; r < 4; ++r) li[r] = 1.f / __shfl(lrow, 4 * g + r);
    #pragma unroll
    for (int j2 = 0; j2 < 4; ++j2)
      #pragma unroll
      for (int r = 0; r < 4; ++r) {
        int q = q0 + w * 16 + 4 * g + r;
        int d = j2 * 16 + fr;
        attn[((size_t)(b * Ss) + q) * Dd + h * 64 + d] = f2b(acc_o[j2][r] * li[r]);
      }
  }
}

// ---------------- 256x256x64 8-phase bf16 GEMM (T2+T3+T4+T5), f32 out + bias
__global__ __launch_bounds__(512, 2) void k_gemm256(
    const u16* __restrict__ A, const u16* __restrict__ Bt,
    const float* __restrict__ bias, float* __restrict__ C,
    int N, int K) {
  __shared__ u16 lA[2][16384];
  __shared__ u16 lB[2][16384];
  const int tid = threadIdx.x;
  const int nwg = gridDim.x;
  const int f = blockIdx.x;
  const int t = (f & 7) * (nwg >> 3) + (f >> 3);   // xcd swizzle (nwg % 8 == 0)
  const long m0 = (long)(t & 7) * 256;
  const long n0 = (long)(t >> 3) * 256;
  const int lane = tid & 63, wid = tid >> 6;
  const int H = wid >> 2, w2 = wid & 3;
  const int fr = lane & 15, l4 = lane >> 4;
  const int NT = K >> 6;

  auto stageA = [&](int buf, int kk, int mh) {
    #pragma unroll
    for (int g = 0; g < 2; ++g) {
      int r6 = tid >> 3;
      int row = g * 128 + mh * 64 + r6;
      int slot = mh * 128 + g * 64 + r6;
      const u16* src = A + (m0 + row) * (long)K + kk + (((tid & 7) ^ (r6 & 7)) << 3);
      gll16(src, &lA[buf][slot * 64 + (tid & 7) * 8]);
    }
  };
  auto stageB = [&](int buf, int kk, int nh) {
    #pragma unroll
    for (int g = 0; g < 2; ++g) {
      int s127 = g * 64 + (tid >> 3);
      int row = (s127 >> 5) * 64 + nh * 32 + (s127 & 31);
      int slot = nh * 128 + s127;
      const u16* src = Bt + (n0 + row) * (long)K + kk + (((tid & 7) ^ (s127 & 7)) << 3);
      gll16(src, &lB[buf][slot * 64 + (tid & 7) * 8]);
    }
  };

  f32x4 acc[8][4] = {};

  stageA(0, 0, 0); stageB(0, 0, 0); stageB(0, 0, 1); stageA(0, 0, 1);
  asm volatile("s_waitcnt vmcnt(4)" ::: "memory");
  __builtin_amdgcn_s_barrier();
  asm volatile("" ::: "memory");

  for (int j = 0; j < NT; ++j) {
    const int cur = j & 1;
    const int kk1 = (j + 1) << 6;
    const bool more = (j + 1 < NT);
    #pragma unroll
    for (int q = 0; q < 4; ++q) {
      const int mh = q >> 1, nh = q & 1;
      bf16x8 af[4][2], bfp[2][2];
      #pragma unroll
      for (int i = 0; i < 4; ++i)
        #pragma unroll
        for (int ks = 0; ks < 2; ++ks) {
          int slot = mh * 128 + H * 64 + i * 16 + fr;
          int c = (ks * 4 + l4) ^ (fr & 7);
          af[i][ks] = *(const bf16x8*)&lA[cur][slot * 64 + c * 8];
        }
      #pragma unroll
      for (int nl = 0; nl < 2; ++nl)
        #pragma unroll
        for (int ks = 0; ks < 2; ++ks) {
          int slot = nh * 128 + w2 * 32 + nl * 16 + fr;
          int c = (ks * 4 + l4) ^ (fr & 7);
          bfp[nl][ks] = *(const bf16x8*)&lB[cur][slot * 64 + c * 8];
        }
      if (more) {
        if (q == 0) stageA(cur ^ 1, kk1, 0);
        else if (q == 1) stageB(cur ^ 1, kk1, 0);
        else if (q == 2) stageB(cur ^ 1, kk1, 1);
        else stageA(cur ^ 1, kk1, 1);
      }
      asm volatile("" ::: "memory");
      __builtin_amdgcn_s_barrier();
      asm volatile("" ::: "memory");
      __builtin_amdgcn_s_setprio(1);
      #pragma unroll
      for (int i = 0; i < 4; ++i)
        #pragma unroll
        for (int nl = 0; nl < 2; ++nl) {
          acc[mh * 4 + i][nh * 2 + nl] = __builtin_amdgcn_mfma_f32_16x16x32_bf16(
              af[i][0], bfp[nl][0], acc[mh * 4 + i][nh * 2 + nl], 0, 0, 0);
          acc[mh * 4 + i][nh * 2 + nl] = __builtin_amdgcn_mfma_f32_16x16x32_bf16(
              af[i][1], bfp[nl][1], acc[mh * 4 + i][nh * 2 + nl], 0, 0, 0);
        }
      __builtin_amdgcn_s_setprio(0);
      if (more) {
        if (q != 2) asm volatile("s_waitcnt vmcnt(4)" ::: "memory");
      } else {
        if (q == 0) asm volatile("s_waitcnt vmcnt(2)" ::: "memory");
        else if (q == 1) asm volatile("s_waitcnt vmcnt(0)" ::: "memory");
      }
      __builtin_amdgcn_s_barrier();
      asm volatile("" ::: "memory");
    }
  }

  const long r0 = m0 + H * 128 + l4 * 4;
  const long c0 = n0 + w2 * 64 + fr;
  #pragma unroll
  for (int ni = 0; ni < 4; ++ni) {
    long col = c0 + ni * 16;
    if (col < N) {
      float bs = bias[col];
      #pragma unroll
      for (int mi = 0; mi < 8; ++mi)
        #pragma unroll
        for (int r = 0; r < 4; ++r)
          C[(r0 + mi * 16 + r) * (long)N + col] = acc[mi][ni][r] + bs;
    }
  }
}

// ---------------- bf16 MFMA GEMM 128xBN (m97 structure)
// MODE 0: f32 C = acc + bias ; MODE 1: f32 C += acc + bias
template <int MODE, int BN, bool SWZ>
__global__ __launch_bounds__(256) void k_gemm(
    const u16* __restrict__ A, const u16* __restrict__ Bt,
    const float* __restrict__ bias, void* __restrict__ C,
    int N, int K, long sA, long sB, long sC) {
  __shared__ u16 lA[128 * 32];
  __shared__ u16 lB[BN * 32];
  const int tid = threadIdx.x;
  const int bz = blockIdx.z;

  int bx, by;
  if (SWZ) {
    int gx = gridDim.x;
    int nwg = gx * gridDim.y;
    int f = blockIdx.y * gx + blockIdx.x;
    int f2 = (f & 7) * (nwg >> 3) + (f >> 3);
    bx = f2 % gx; by = f2 / gx;
  } else {
    bx = blockIdx.x; by = blockIdx.y;
  }
  const long m0 = (long)bx * 128, n0 = (long)by * BN;

  const u16* Az = A + (size_t)bz * sA;
  const u16* Bz = Bt + (size_t)bz * sB;
  const int srow = tid >> 2;
  const int scol = (tid & 3) << 3;
  const u16* a0 = Az + (m0 + srow) * (long)K + scol;
  const u16* b0 = Bz + (n0 + srow) * (long)K + scol;
  const long rstep = 64L * K;

  const int lane = tid & 63, wid = tid >> 6;
  constexpr int WR = (BN == 128) ? 64 : 32;
  constexpr int MI = WR / 16;
  const int wm = (BN == 128) ? (wid >> 1) * 64 : wid * 32;
  const int wn = (BN == 128) ? (wid & 1) * 64 : 0;
  const int fr = lane & 15, kg = (lane >> 4) * 8;

  f32x4 acc[MI][4] = {};

  for (int kk = 0; kk < K; kk += 32) {
    gll16(a0 + kk, lA + tid * 8);
    gll16(a0 + rstep + kk, lA + 2048 + tid * 8);
    gll16(b0 + kk, lB + tid * 8);
    if (BN == 128) gll16(b0 + rstep + kk, lB + 2048 + tid * 8);
    __syncthreads();
    bf16x8 af[MI], bfr[4];
    #pragma unroll
    for (int i = 0; i < MI; i++) af[i] = *(const bf16x8*)&lA[(wm + i * 16 + fr) * 32 + kg];
    #pragma unroll
    for (int j = 0; j < 4; j++) bfr[j] = *(const bf16x8*)&lB[(wn + j * 16 + fr) * 32 + kg];
    #pragma unroll
    for (int i = 0; i < MI; i++)
      #pragma unroll
      for (int j = 0; j < 4; j++)
        acc[i][j] = __builtin_amdgcn_mfma_f32_16x16x32_bf16(af[i], bfr[j], acc[i][j], 0, 0, 0);
    __syncthreads();
  }

  const int rb = wm + ((lane >> 4) << 2);
  const int cb = wn + (lane & 15);
  #pragma unroll
  for (int j = 0; j < 4; j++) {
    long gcol = n0 + cb + j * 16;
    float bs = 0.f;
    if (gcol < N) bs = bias[gcol];
    #pragma unroll
    for (int i = 0; i < MI; i++) {
      #pragma unroll
      for (int r = 0; r < 4; r++) {
        long grow = m0 + rb + i * 16 + r;
        float val = acc[i][j][r];
        if (MODE == 0) {
          if (gcol < N) ((float*)C)[grow * N + gcol] = val + bs;
        } else {
          if (gcol < N) { float* p = (float*)C + grow * N + gcol; *p += val + bs; }
        }
      }
    }
  }
}

// ---------------- silu gate: uv (2048 x 5632 f32) -> gated bf16 (2048 x 2816)
__global__ void k_silu(const float* __restrict__ uv, u16* __restrict__ g) {
  int n = blockIdx.x * 256 + threadIdx.x;
  int m = blockIdx.y;
  float u = uv[(size_t)m * 5632 + n];
  float x = uv[(size_t)m * 5632 + 2816 + n];
  float sg = 1.f / (1.f + __expf(-x));
  g[(size_t)m * 2816 + n] = f2b(u * x * sg);
}

extern "C" void kernel_launch(void* const* d_in, const int* in_sizes, int n_in,
                              void* d_out, int out_size, void* d_ws, size_t ws_size,
                              hipStream_t stream) {
  (void)in_sizes; (void)n_in; (void)out_size; (void)ws_size;
  const int*   tokens    = (const int*)  d_in[0];
  const float* embed     = (const float*)d_in[1];
  const float* w_kv_down = (const float*)d_in[2];
  const float* b_kv_down = (const float*)d_in[3];
  const float* w_q_down  = (const float*)d_in[4];
  const float* b_q_down  = (const float*)d_in[5];
  const float* w_kv_up   = (const float*)d_in[6];
  const float* b_kv_up   = (const float*)d_in[7];
  const float* w_q_up    = (const float*)d_in[8];
  const float* b_q_up    = (const float*)d_in[9];
  const float* w_o       = (const float*)d_in[10];
  const float* b_o       = (const float*)d_in[11];
  const float* kv_norm_w = (const float*)d_in[12];
  const float* q_norm_w  = (const float*)d_in[13];
  const float* norm1_w   = (const float*)d_in[14];
  const float* norm2_w   = (const float*)d_in[15];
  const float* w_in      = (const float*)d_in[16];
  const float* b_in      = (const float*)d_in[17];
  const float* w_out     = (const float*)d_in[18];
  const float* b_out     = (const float*)d_in[19];
  const float* norm_f_w  = (const float*)d_in[20];
  const float* w_head    = (const float*)d_in[21];
  const float* b_head    = (const float*)d_in[22];

  char* base = (char*)d_ws;
  size_t off = 0;
  auto alloc = [&](size_t bytes) -> void* {
    void* p = base + off;
    off += (bytes + 255) & ~(size_t)255;
    return p;
  };
  u16* warena = (u16*)alloc((size_t)32000 * 1024 * 2);
  u16* wT_dq    = warena;                        // 768 x 1024
  u16* wT_kvup  = wT_dq   + 768 * 1024;          // 2048 x 256
  u16* wT_qup   = wT_kvup + 2048 * 256;          // 1536 x 384
  u16* wT_o     = wT_qup  + 1536 * 384;          // 1024 x 1024
  u16* wT_in    = wT_o    + 1024 * 1024;         // 5632 x 1024
  u16* wT_out   = wT_in   + 5632 * 1024;         // 1024 x 2816

  float* h     = (float*)alloc((size_t)Mm * 1024 * 4);
  u16*   xn    = (u16*)  alloc((size_t)Mm * 1024 * 2);
  float* ckvq  = (float*)alloc((size_t)Mm * 768 * 4);
  float* bdq   = (float*)alloc(768 * 4);
  u16*   ckvn  = (u16*)  alloc((size_t)Mm * 256 * 2);
  float* kv    = (float*)alloc((size_t)Mm * 2048 * 4);
  u16*   qdn   = (u16*)  alloc((size_t)Mm * 384 * 2);
  float* qf    = (float*)alloc((size_t)Mm * 1536 * 4);
  u16*   Qb    = (u16*)  alloc((size_t)32 * 1024 * QKD * 2);
  u16*   Kb    = (u16*)  alloc((size_t)32 * 1024 * QKD * 2);
  u16*   Vt    = (u16*)  alloc((size_t)32 * 64 * 1024 * 2);
  float* uvb   = (float*)alloc((size_t)Mm * 5632 * 4);
  u16*   attn  = (u16*)  alloc((size_t)Mm * 1024 * 2);
  u16*   gate  = (u16*)  alloc((size_t)Mm * 2816 * 2);

  dim3 tb(32, 8);
  auto cvt = [&](const float* src, u16* dst, int K, int N, int Npad) {
    dim3 gg(K / 32, Npad / 32);
    k_wcvt<<<gg, tb, 0, stream>>>(src, dst, K, N, Npad);
  };

  k_embed<<<Mm, 256, 0, stream>>>(tokens, embed, h);

  for (int l = 0; l < 4; l++) {
    cvt(w_kv_down + (size_t)l * 1024 * 288,  wT_dq,            1024, 288, 384);
    cvt(w_q_down  + (size_t)l * 1024 * 384,  wT_dq + 384*1024, 1024, 384, 384);
    cvt(w_kv_up   + (size_t)l * 256 * 2048,  wT_kvup,          256, 2048, 2048);
    cvt(w_q_up    + (size_t)l * 384 * 1536,  wT_qup,           384, 1536, 1536);
    cvt(w_o       + (size_t)l * 1024 * 1024, wT_o,             1024, 1024, 1024);
    cvt(w_in      + (size_t)l * 1024 * 5632, wT_in,            1024, 5632, 5632);
    cvt(w_out     + (size_t)l * 2816 * 1024, wT_out,           2816, 1024, 1024);
    k_biascat<<<3, 256, 0, stream>>>(b_kv_down + l * 288, b_q_down + l * 384, bdq);

    k_rms<<<Mm, 256, 0, stream>>>(h, 1024, norm1_w + l * 1024, xn, 1024);
    k_gemm<0, 64, true><<<dim3(16, 12), 256, 0, stream>>>(xn, wT_dq, bdq,
                                                          ckvq, 768, 1024, 0, 0, 0);
    k_rms<<<Mm, 256, 0, stream>>>(ckvq, 768, kv_norm_w + l * 256, ckvn, 256);
    k_gemm<0, 128, true><<<dim3(16, 16), 256, 0, stream>>>(ckvn, wT_kvup, b_kv_up + l * 2048,
                                                           kv, 2048, 256, 0, 0, 0);
    k_rms<<<Mm, 256, 0, stream>>>(ckvq + 384, 768, q_norm_w + l * 384, qdn, 384);
    k_gemm<0, 128, true><<<dim3(16, 12), 256, 0, stream>>>(qdn, wT_qup, b_q_up + l * 1536,
                                                           qf, 1536, 384, 0, 0, 0);
    k_buildq<<<dim3(Ss, 32), 128, 0, stream>>>(qf, Qb);
    k_buildk<<<dim3(Ss, 32), 128, 0, stream>>>(kv, ckvq, Kb);
    k_buildvt<<<dim3(32, 32, 2), tb, 0, stream>>>(kv, Vt);
    k_flash<<<dim3(8, 32), 256, 0, stream>>>(Qb, Kb, Vt, attn);
    k_gemm<1, 64, true><<<dim3(16, 16), 256, 0, stream>>>(attn, wT_o, b_o + l * 1024,
                                                          h, 1024, 1024, 0, 0, 0);
    k_rms<<<Mm, 256, 0, stream>>>(h, 1024, norm2_w + l * 1024, xn, 1024);
    k_gemm256<<<176, 512, 0, stream>>>(xn, wT_in, b_in + l * 5632, uvb, 5632, 1024);
    k_silu<<<dim3(11, Mm), 256, 0, stream>>>(uvb, gate);
    k_gemm<1, 64, true><<<dim3(16, 16), 256, 0, stream>>>(gate, wT_out, b_out + l * 1024,
                                                          h, 1024, 2816, 0, 0, 0);
  }

  k_rms<<<Mm, 256, 0, stream>>>(h, 1024, norm_f_w, xn, 1024);
  cvt(w_head, warena, 1024, 32000, 32000);
  k_gemm256<<<1000, 512, 0, stream>>>(xn, warena, b_head, (float*)d_out, 32000, 1024);
}

// Round 5
// 1419.588 us; speedup vs baseline: 1.2426x; 1.0300x over previous
//
#include <hip/hip_runtime.h>
#include <cstdint>
#include <cstddef>

typedef unsigned short u16;
typedef __attribute__((__ext_vector_type__(8))) __bf16 bf16x8;
typedef __attribute__((__ext_vector_type__(4))) float f32x4;
typedef __attribute__((__ext_vector_type__(8))) unsigned short u16x8;

#define DEVI __device__ __forceinline__

constexpr int Bb = 2, Ss = 1024, Dd = 1024, Hh = 16;
constexpr int Mm = Bb * Ss;       // 2048 token rows
constexpr int QKD = 128;          // padded q/k head dim (96 -> 128, zero pad)
constexpr float EPSF = 1.1920929e-07f;
constexpr float NEG = -1e30f;
constexpr float QSCALE = 0.10206207261596577f; // 1/sqrt(96)
constexpr float LOG1E4_16 = 9.210340371976184f / 16.f;

DEVI u16 f2b(float f) {
  union { float f; uint32_t u; } a; a.f = f;
  uint32_t r = a.u + 0x7FFFu + ((a.u >> 16) & 1u);
  return (u16)(r >> 16);
}
DEVI float b2f(u16 h) {
  union { uint32_t u; float f; } a; a.u = ((uint32_t)h) << 16; return a.f;
}

// ---------------- fp32 -> bf16 transposed weight conversion (K x N -> Npad x K)
__global__ void k_wcvt(const float* __restrict__ in, u16* __restrict__ out,
                       int K, int N, int Npad) {
  __shared__ float t[32][33];
  int bk = blockIdx.x * 32, bn = blockIdx.y * 32;
  int tx = threadIdx.x, ty = threadIdx.y;
  #pragma unroll
  for (int i = ty; i < 32; i += 8) {
    int n = bn + tx;
    t[i][tx] = (n < N) ? in[(size_t)(bk + i) * N + n] : 0.f;
  }
  __syncthreads();
  #pragma unroll
  for (int i = ty; i < 32; i += 8) {
    int n = bn + i;
    out[(size_t)n * K + bk + tx] = f2b(t[tx][i]);
  }
}

// ---------------- fp32 -> bf16 transpose for w_in with u/x pair interleave:
// out row n <- src col (n odd ? n/2 + 2816 : n/2)
__global__ void k_wcvt_perm(const float* __restrict__ in, u16* __restrict__ out,
                            int K) {
  __shared__ float t[32][33];
  int bk = blockIdx.x * 32, bn = blockIdx.y * 32;
  int tx = threadIdx.x, ty = threadIdx.y;
  #pragma unroll
  for (int i = ty; i < 32; i += 8) {
    int n = bn + tx;
    int src = (n & 1) ? (n >> 1) + 2816 : (n >> 1);
    t[i][tx] = in[(size_t)(bk + i) * 5632 + src];
  }
  __syncthreads();
  #pragma unroll
  for (int i = ty; i < 32; i += 8) {
    int n = bn + i;
    out[(size_t)n * K + bk + tx] = f2b(t[tx][i]);
  }
}

// ---------------- embedding gather
__global__ void k_embed(const int* __restrict__ tok, const float* __restrict__ emb,
                        float* __restrict__ h) {
  int m = blockIdx.x;
  int t = tok[m];
  const float4* src = (const float4*)(emb + (size_t)t * Dd);
  float4* dst = (float4*)(h + (size_t)m * Dd);
  dst[threadIdx.x] = src[threadIdx.x];
}

// ---------------- rmsnorm: f32 (stride inStride) -> bf16 (stride K)
__global__ void k_rms(const float* __restrict__ in, int inStride,
                      const float* __restrict__ w, u16* __restrict__ out, int K) {
  int m = blockIdx.x;
  const float* x = in + (size_t)m * inStride;
  float ss = 0.f;
  for (int i = threadIdx.x; i < K; i += 256) { float v = x[i]; ss += v * v; }
  #pragma unroll
  for (int off = 32; off; off >>= 1) ss += __shfl_xor(ss, off);
  __shared__ float red[4];
  if ((threadIdx.x & 63) == 0) red[threadIdx.x >> 6] = ss;
  __syncthreads();
  float r = rsqrtf((red[0] + red[1] + red[2] + red[3]) / (float)K + EPSF);
  for (int i = threadIdx.x; i < K; i += 256)
    out[(size_t)m * K + i] = f2b(x[i] * r * w[i]);
}

// ---------------- bias concat for fused down-proj (288 kv | pad | 384 q)
__global__ void k_biascat(const float* __restrict__ b1, const float* __restrict__ b2,
                          float* __restrict__ out) {
  int i = blockIdx.x * 256 + threadIdx.x;  // 0..767
  float v = 0.f;
  if (i < 288) v = b1[i];
  else if (i >= 384) v = b2[i - 384];
  out[i] = v;
}

// ---------------- build Q (rope on cols 64..95, *QSCALE, pad to 128)
__global__ void k_buildq(const float* __restrict__ qf, u16* __restrict__ Q) {
  int s = blockIdx.x, bh = blockIdx.y;
  int b = bh >> 4, h = bh & 15;
  int d = threadIdx.x;
  const float* row = qf + (size_t)(b * Ss + s) * (Hh * 96) + h * 96;
  float v = 0.f;
  if (d < 64) v = row[d];
  else if (d < 96) {
    int j = d - 64;
    int jj = j & 15;
    float theta = __expf(-(float)jj * LOG1E4_16);
    float ang = (float)s * theta;
    float sn, cs; __sincosf(ang, &sn, &cs);
    float x = row[64 + j];
    float o = row[64 + (j ^ 16)];
    v = x * cs + ((j < 16) ? -o : o) * sn;
  }
  Q[((size_t)bh * Ss + s) * QKD + d] = f2b(v * QSCALE);
}

// ---------------- build K (k from kv, roped k_rope from fused ckvq, bcast over heads)
__global__ void k_buildk(const float* __restrict__ kv, const float* __restrict__ ckvq,
                         u16* __restrict__ Kb) {
  int s = blockIdx.x, bh = blockIdx.y;
  int b = bh >> 4, h = bh & 15;
  int d = threadIdx.x;
  int m = b * Ss + s;
  float v = 0.f;
  if (d < 64) v = kv[(size_t)m * 2048 + h * 128 + d];
  else if (d < 96) {
    int j = d - 64;
    int jj = j & 15;
    float theta = __expf(-(float)jj * LOG1E4_16);
    float ang = (float)s * theta;
    float sn, cs; __sincosf(ang, &sn, &cs);
    const float* rr = ckvq + (size_t)m * 768 + 256;
    float x = rr[j];
    float o = rr[j ^ 16];
    v = x * cs + ((j < 16) ? -o : o) * sn;
  }
  Kb[((size_t)bh * Ss + s) * QKD + d] = f2b(v);
}

// ---------------- build V^T (per head: [64][1024]), bf16
__global__ void k_buildvt(const float* __restrict__ kv, u16* __restrict__ Vt) {
  __shared__ float t[32][33];
  int bh = blockIdx.x, s0 = blockIdx.y * 32, d0 = blockIdx.z * 32;
  int b = bh >> 4, h = bh & 15;
  int tx = threadIdx.x, ty = threadIdx.y;
  #pragma unroll
  for (int i = ty; i < 32; i += 8) {
    int s = s0 + i, d = d0 + tx;
    t[i][tx] = kv[(size_t)(b * Ss + s) * 2048 + h * 128 + 64 + d];
  }
  __syncthreads();
  #pragma unroll
  for (int i = ty; i < 32; i += 8) {
    int d = d0 + i, s = s0 + tx;
    Vt[((size_t)bh * 64 + d) * Ss + s] = f2b(t[tx][i]);
  }
}

#define GAS __attribute__((address_space(1)))
#define LAS __attribute__((address_space(3)))
DEVI void gll16(const void* g, void* l) {
  __builtin_amdgcn_global_load_lds((GAS const void*)g, (LAS void*)l, 16, 0, 0);
}

// ---------------- fused flash attention (causal), bf16 in/out
__global__ __launch_bounds__(256) void k_flash(
    const u16* __restrict__ Qg, const u16* __restrict__ Kg,
    const u16* __restrict__ Vtg, u16* __restrict__ attn) {
  __shared__ u16 lK[64 * 128];
  __shared__ u16 lV[64 * 64];
  __shared__ u16 lP[4][16 * 64];
  const int tid = threadIdx.x;
  const int pair = blockIdx.x, bh = blockIdx.y;
  const int b = bh >> 4, h = bh & 15;
  const int lane = tid & 63, w = tid >> 6;
  const int g = lane >> 4, fr = lane & 15;
  const u16* Qh = Qg + (size_t)bh * Ss * QKD;
  const u16* Kh = Kg + (size_t)bh * Ss * QKD;
  const u16* Vh = Vtg + (size_t)bh * 64 * Ss;

  for (int pass = 0; pass < 2; ++pass) {
    const int qt = pass ? (15 - pair) : pair;
    const int q0 = qt * 64;
    bf16x8 af[4];
    const u16* qrow = Qh + (size_t)(q0 + w * 16 + fr) * QKD + g * 8;
    #pragma unroll
    for (int k4 = 0; k4 < 4; ++k4) af[k4] = *(const bf16x8*)(qrow + k4 * 32);

    f32x4 acc_o[4] = {};
    float mrow = NEG, lrow = 0.f;

    for (int kt = 0; kt <= qt; ++kt) {
      {
        int r = tid >> 4, c = tid & 15;
        #pragma unroll
        for (int gg = 0; gg < 4; ++gg) {
          int row = gg * 16 + r;
          const u16* src = Kh + (size_t)(kt * 64 + row) * QKD + ((c ^ (row & 7)) * 8);
          gll16(src, (u16*)lK + gg * 2048 + tid * 8);
        }
        int r2 = tid >> 3, c2 = tid & 7;
        #pragma unroll
        for (int gg = 0; gg < 2; ++gg) {
          int d = gg * 32 + r2;
          const u16* src = Vh + (size_t)d * Ss + kt * 64 + ((c2 ^ (d & 7)) * 8);
          gll16(src, (u16*)lV + gg * 2048 + tid * 8);
        }
      }
      asm volatile("s_waitcnt vmcnt(0)" ::: "memory");
      __builtin_amdgcn_s_barrier();
      asm volatile("" ::: "memory");

      f32x4 accs[4] = {};
      #pragma unroll
      for (int j = 0; j < 4; ++j) {
        #pragma unroll
        for (int k4 = 0; k4 < 4; ++k4) {
          int row = j * 16 + fr;
          int ch = (k4 * 4 + g) ^ (row & 7);
          bf16x8 kf = *(const bf16x8*)&lK[row * 128 + ch * 8];
          accs[j] = __builtin_amdgcn_mfma_f32_16x16x32_bf16(kf, af[k4], accs[j], 0, 0, 0);
        }
      }

      float p[16];
      float tmax = NEG;
      #pragma unroll
      for (int j = 0; j < 4; ++j)
        #pragma unroll
        for (int r = 0; r < 4; ++r) {
          float s = accs[j][r];
          int kloc = j * 16 + 4 * g + r;
          bool valid = (kt < qt) || (kloc <= w * 16 + fr);
          s = valid ? s : NEG;
          p[j * 4 + r] = s;
          tmax = fmaxf(tmax, s);
        }
      tmax = fmaxf(tmax, __shfl_xor(tmax, 16));
      tmax = fmaxf(tmax, __shfl_xor(tmax, 32));
      float mnew = fmaxf(mrow, tmax);
      float scale = __expf(mrow - mnew);
      float tsum = 0.f;
      #pragma unroll
      for (int i = 0; i < 16; ++i) { p[i] = __expf(p[i] - mnew); tsum += p[i]; }
      tsum += __shfl_xor(tsum, 16);
      tsum += __shfl_xor(tsum, 32);
      lrow = lrow * scale + tsum;
      mrow = mnew;

      #pragma unroll
      for (int j = 0; j < 4; ++j)
        #pragma unroll
        for (int t = 0; t < 2; ++t) {
          uint32_t u = (uint32_t)f2b(p[j * 4 + 2 * t]) |
                       ((uint32_t)f2b(p[j * 4 + 2 * t + 1]) << 16);
          int kp = 8 * j + 2 * g + t;
          int ch = kp >> 2, wi = kp & 3;
          ((uint32_t*)lP[w])[fr * 32 + ((ch ^ (fr & 7)) << 2) + wi] = u;
        }

      float sc_q[4];
      #pragma unroll
      for (int r = 0; r < 4; ++r) sc_q[r] = __shfl(scale, 4 * g + r);
      #pragma unroll
      for (int j2 = 0; j2 < 4; ++j2)
        #pragma unroll
        for (int r = 0; r < 4; ++r) acc_o[j2][r] *= sc_q[r];

      #pragma unroll
      for (int ksub = 0; ksub < 2; ++ksub) {
        int chp = (4 * ksub + g) ^ (fr & 7);
        bf16x8 pa = *(const bf16x8*)&((const u16*)lP[w])[fr * 64 + chp * 8];
        #pragma unroll
        for (int j2 = 0; j2 < 4; ++j2) {
          int d = j2 * 16 + fr;
          int chv = (ksub * 4 + g) ^ (d & 7);
          bf16x8 vf = *(const bf16x8*)&lV[d * 64 + chv * 8];
          acc_o[j2] = __builtin_amdgcn_mfma_f32_16x16x32_bf16(pa, vf, acc_o[j2], 0, 0, 0);
        }
      }
      asm volatile("" ::: "memory");
      __builtin_amdgcn_s_barrier();
      asm volatile("" ::: "memory");
    }

    float li[4];
    #pragma unroll
    for (int r = 0; r < 4; ++r) li[r] = 1.f / __shfl(lrow, 4 * g + r);
    #pragma unroll
    for (int j2 = 0; j2 < 4; ++j2)
      #pragma unroll
      for (int r = 0; r < 4; ++r) {
        int q = q0 + w * 16 + 4 * g + r;
        int d = j2 * 16 + fr;
        attn[((size_t)(b * Ss) + q) * Dd + h * 64 + d] = f2b(acc_o[j2][r] * li[r]);
      }
  }
}

// ---------------- 256x256x64 8-phase bf16 GEMM (T2+T3+T4+T5)
// MODE 0: f32 C = acc + bias
// MODE 1: silu-fused (w_in with pair-interleaved Bt): bf16 gate out [M][2816]
#define BAR256 do { asm volatile("" ::: "memory"); __builtin_amdgcn_s_barrier(); \
                    asm volatile("" ::: "memory"); } while (0)
#define VMW(n) asm volatile("s_waitcnt vmcnt(" #n ")" ::: "memory")

#define LD_A(mh_) { \
  _Pragma("unroll") \
  for (int i = 0; i < 4; ++i) { \
    _Pragma("unroll") \
    for (int ks = 0; ks < 2; ++ks) { \
      int slot = (mh_) * 128 + H * 64 + i * 16 + fr; \
      int c = (ks * 4 + l4) ^ (fr & 7); \
      fa[i][ks] = *(const bf16x8*)&lA[cur][slot * 64 + c * 8]; \
    } \
  } \
}
#define LD_B(dst, nh_) { \
  _Pragma("unroll") \
  for (int nl = 0; nl < 2; ++nl) { \
    _Pragma("unroll") \
    for (int ks = 0; ks < 2; ++ks) { \
      int slot = (nh_) * 128 + w2 * 32 + nl * 16 + fr; \
      int c = (ks * 4 + l4) ^ (fr & 7); \
      dst[nl][ks] = *(const bf16x8*)&lB[cur][slot * 64 + c * 8]; \
    } \
  } \
}
#define MFQ(fx, mh_, nh_) { \
  __builtin_amdgcn_s_setprio(1); \
  _Pragma("unroll") \
  for (int i = 0; i < 4; ++i) { \
    _Pragma("unroll") \
    for (int nl = 0; nl < 2; ++nl) { \
      acc[(mh_) * 4 + i][(nh_) * 2 + nl] = __builtin_amdgcn_mfma_f32_16x16x32_bf16( \
          fa[i][0], fx[nl][0], acc[(mh_) * 4 + i][(nh_) * 2 + nl], 0, 0, 0); \
      acc[(mh_) * 4 + i][(nh_) * 2 + nl] = __builtin_amdgcn_mfma_f32_16x16x32_bf16( \
          fa[i][1], fx[nl][1], acc[(mh_) * 4 + i][(nh_) * 2 + nl], 0, 0, 0); \
    } \
  } \
  __builtin_amdgcn_s_setprio(0); \
}

template <int MODE>
__global__ __launch_bounds__(512, 2) void k_gemm256(
    const u16* __restrict__ A, const u16* __restrict__ Bt,
    const float* __restrict__ bias, void* __restrict__ Cv,
    int N, int K) {
  __shared__ u16 lA[2][16384];
  __shared__ u16 lB[2][16384];
  const int tid = threadIdx.x;
  const int nwg = gridDim.x;
  const int f = blockIdx.x;
  const int t = (f & 7) * (nwg >> 3) + (f >> 3);   // xcd swizzle (nwg % 8 == 0)
  const long m0 = (long)(t & 7) * 256;
  const long n0 = (long)(t >> 3) * 256;
  const int lane = tid & 63, wid = tid >> 6;
  const int H = wid >> 2, w2 = wid & 3;
  const int fr = lane & 15, l4 = lane >> 4;
  const int NT = K >> 6;

  auto stageA = [&](int buf, int kk, int mh) {
    #pragma unroll
    for (int g = 0; g < 2; ++g) {
      int r6 = tid >> 3;
      int row = g * 128 + mh * 64 + r6;
      int slot = mh * 128 + g * 64 + r6;
      const u16* src = A + (m0 + row) * (long)K + kk + (((tid & 7) ^ (r6 & 7)) << 3);
      gll16(src, &lA[buf][slot * 64 + (tid & 7) * 8]);
    }
  };
  auto stageB = [&](int buf, int kk, int nh) {
    #pragma unroll
    for (int g = 0; g < 2; ++g) {
      int s127 = g * 64 + (tid >> 3);
      int row = (s127 >> 5) * 64 + nh * 32 + (s127 & 31);
      int slot = nh * 128 + s127;
      const u16* src = Bt + (n0 + row) * (long)K + kk + (((tid & 7) ^ (s127 & 7)) << 3);
      gll16(src, &lB[buf][slot * 64 + (tid & 7) * 8]);
    }
  };

  f32x4 acc[8][4] = {};
  bf16x8 fa[4][2], fb0[2][2], fb1[2][2];

  // prologue: tile 0 -> buf0, consumption order Au0, Bu0, Bu1, Au1
  stageA(0, 0, 0); stageB(0, 0, 0); stageB(0, 0, 1); stageA(0, 0, 1);
  VMW(4);   // Au0, Bu0 landed
  BAR256;

  for (int j = 0; j < NT; ++j) {
    const int cur = j & 1, nxt = cur ^ 1;
    const int kk1 = (j + 1) << 6;
    const bool more = (j + 1 < NT);
    // ---- ph0: read A0+B0, stage Au0', mfma quad(0,0)
    LD_A(0); LD_B(fb0, 0);
    if (more) stageA(nxt, kk1, 0);
    BAR256;
    MFQ(fb0, 0, 0);
    if (more) { VMW(4); } else { VMW(2); }
    BAR256;
    // ---- ph1: read B1, stage Bu0', mfma quad(0,1)
    LD_B(fb1, 1);
    if (more) stageB(nxt, kk1, 0);
    BAR256;
    MFQ(fb1, 0, 1);
    if (more) { VMW(4); } else { VMW(0); }
    BAR256;
    // ---- ph2: read A1, stage Bu1', mfma quad(1,1)
    LD_A(1);
    if (more) stageB(nxt, kk1, 1);
    BAR256;
    MFQ(fb1, 1, 1);
    BAR256;
    // ---- ph3: re-read B0, stage Au1', mfma quad(1,0)
    LD_B(fb0, 0);
    if (more) stageA(nxt, kk1, 1);
    BAR256;
    MFQ(fb0, 1, 0);
    if (more) { VMW(4); }
    BAR256;
  }

  const long r0 = m0 + H * 128 + l4 * 4;
  const long c0 = n0 + w2 * 64 + fr;
  if (MODE == 0) {
    float* C = (float*)Cv;
    #pragma unroll
    for (int ni = 0; ni < 4; ++ni) {
      long col = c0 + ni * 16;
      if (col < N) {
        float bs = bias[col];
        #pragma unroll
        for (int mi = 0; mi < 8; ++mi)
          #pragma unroll
          for (int r = 0; r < 4; ++r)
            C[(r0 + mi * 16 + r) * (long)N + col] = acc[mi][ni][r] + bs;
      }
    }
  } else {
    u16* G = (u16*)Cv;
    #pragma unroll
    for (int ni = 0; ni < 4; ++ni) {
      long col = c0 + ni * 16;
      int pcol = (int)((col & 1) ? (col >> 1) + 2816 : (col >> 1));
      float bs = bias[pcol];
      #pragma unroll
      for (int mi = 0; mi < 8; ++mi)
        #pragma unroll
        for (int r = 0; r < 4; ++r) {
          float val = acc[mi][ni][r] + bs;
          float oth = __shfl_xor(val, 1);
          if (!(col & 1)) {
            float x = oth;
            float gv = val * x * (1.f / (1.f + __expf(-x)));
            G[(r0 + mi * 16 + r) * 2816L + (col >> 1)] = f2b(gv);
          }
        }
    }
  }
}

// ---------------- bf16 MFMA GEMM 128xBN (m97 structure)
// MODE 0: f32 C = acc + bias ; MODE 1: f32 C += acc + bias
template <int MODE, int BN, bool SWZ>
__global__ __launch_bounds__(256) void k_gemm(
    const u16* __restrict__ A, const u16* __restrict__ Bt,
    const float* __restrict__ bias, void* __restrict__ C,
    int N, int K, long sA, long sB, long sC) {
  __shared__ u16 lA[128 * 32];
  __shared__ u16 lB[BN * 32];
  const int tid = threadIdx.x;
  const int bz = blockIdx.z;

  int bx, by;
  if (SWZ) {
    int gx = gridDim.x;
    int nwg = gx * gridDim.y;
    int f = blockIdx.y * gx + blockIdx.x;
    int f2 = (f & 7) * (nwg >> 3) + (f >> 3);
    bx = f2 % gx; by = f2 / gx;
  } else {
    bx = blockIdx.x; by = blockIdx.y;
  }
  const long m0 = (long)bx * 128, n0 = (long)by * BN;

  const u16* Az = A + (size_t)bz * sA;
  const u16* Bz = Bt + (size_t)bz * sB;
  const int srow = tid >> 2;
  const int scol = (tid & 3) << 3;
  const u16* a0 = Az + (m0 + srow) * (long)K + scol;
  const u16* b0 = Bz + (n0 + srow) * (long)K + scol;
  const long rstep = 64L * K;

  const int lane = tid & 63, wid = tid >> 6;
  constexpr int WR = (BN == 128) ? 64 : 32;
  constexpr int MI = WR / 16;
  const int wm = (BN == 128) ? (wid >> 1) * 64 : wid * 32;
  const int wn = (BN == 128) ? (wid & 1) * 64 : 0;
  const int fr = lane & 15, kg = (lane >> 4) * 8;

  f32x4 acc[MI][4] = {};

  for (int kk = 0; kk < K; kk += 32) {
    gll16(a0 + kk, lA + tid * 8);
    gll16(a0 + rstep + kk, lA + 2048 + tid * 8);
    gll16(b0 + kk, lB + tid * 8);
    if (BN == 128) gll16(b0 + rstep + kk, lB + 2048 + tid * 8);
    __syncthreads();
    bf16x8 af[MI], bfr[4];
    #pragma unroll
    for (int i = 0; i < MI; i++) af[i] = *(const bf16x8*)&lA[(wm + i * 16 + fr) * 32 + kg];
    #pragma unroll
    for (int j = 0; j < 4; j++) bfr[j] = *(const bf16x8*)&lB[(wn + j * 16 + fr) * 32 + kg];
    #pragma unroll
    for (int i = 0; i < MI; i++)
      #pragma unroll
      for (int j = 0; j < 4; j++)
        acc[i][j] = __builtin_amdgcn_mfma_f32_16x16x32_bf16(af[i], bfr[j], acc[i][j], 0, 0, 0);
    __syncthreads();
  }

  const int rb = wm + ((lane >> 4) << 2);
  const int cb = wn + (lane & 15);
  #pragma unroll
  for (int j = 0; j < 4; j++) {
    long gcol = n0 + cb + j * 16;
    float bs = 0.f;
    if (gcol < N) bs = bias[gcol];
    #pragma unroll
    for (int i = 0; i < MI; i++) {
      #pragma unroll
      for (int r = 0; r < 4; r++) {
        long grow = m0 + rb + i * 16 + r;
        float val = acc[i][j][r];
        if (MODE == 0) {
          if (gcol < N) ((float*)C)[grow * N + gcol] = val + bs;
        } else {
          if (gcol < N) { float* p = (float*)C + grow * N + gcol; *p += val + bs; }
        }
      }
    }
  }
}

extern "C" void kernel_launch(void* const* d_in, const int* in_sizes, int n_in,
                              void* d_out, int out_size, void* d_ws, size_t ws_size,
                              hipStream_t stream) {
  (void)in_sizes; (void)n_in; (void)out_size; (void)ws_size;
  const int*   tokens    = (const int*)  d_in[0];
  const float* embed     = (const float*)d_in[1];
  const float* w_kv_down = (const float*)d_in[2];
  const float* b_kv_down = (const float*)d_in[3];
  const float* w_q_down  = (const float*)d_in[4];
  const float* b_q_down  = (const float*)d_in[5];
  const float* w_kv_up   = (const float*)d_in[6];
  const float* b_kv_up   = (const float*)d_in[7];
  const float* w_q_up    = (const float*)d_in[8];
  const float* b_q_up    = (const float*)d_in[9];
  const float* w_o       = (const float*)d_in[10];
  const float* b_o       = (const float*)d_in[11];
  const float* kv_norm_w = (const float*)d_in[12];
  const float* q_norm_w  = (const float*)d_in[13];
  const float* norm1_w   = (const float*)d_in[14];
  const float* norm2_w   = (const float*)d_in[15];
  const float* w_in      = (const float*)d_in[16];
  const float* b_in      = (const float*)d_in[17];
  const float* w_out     = (const float*)d_in[18];
  const float* b_out     = (const float*)d_in[19];
  const float* norm_f_w  = (const float*)d_in[20];
  const float* w_head    = (const float*)d_in[21];
  const float* b_head    = (const float*)d_in[22];

  char* base = (char*)d_ws;
  size_t off = 0;
  auto alloc = [&](size_t bytes) -> void* {
    void* p = base + off;
    off += (bytes + 255) & ~(size_t)255;
    return p;
  };
  u16* warena = (u16*)alloc((size_t)32000 * 1024 * 2);
  u16* wT_dq    = warena;                        // 768 x 1024
  u16* wT_kvup  = wT_dq   + 768 * 1024;          // 2048 x 256
  u16* wT_qup   = wT_kvup + 2048 * 256;          // 1536 x 384
  u16* wT_o     = wT_qup  + 1536 * 384;          // 1024 x 1024
  u16* wT_in    = wT_o    + 1024 * 1024;         // 5632 x 1024 (pair-interleaved)
  u16* wT_out   = wT_in   + 5632 * 1024;         // 1024 x 2816

  float* h     = (float*)alloc((size_t)Mm * 1024 * 4);
  u16*   xn    = (u16*)  alloc((size_t)Mm * 1024 * 2);
  float* ckvq  = (float*)alloc((size_t)Mm * 768 * 4);
  float* bdq   = (float*)alloc(768 * 4);
  u16*   ckvn  = (u16*)  alloc((size_t)Mm * 256 * 2);
  float* kv    = (float*)alloc((size_t)Mm * 2048 * 4);
  u16*   qdn   = (u16*)  alloc((size_t)Mm * 384 * 2);
  float* qf    = (float*)alloc((size_t)Mm * 1536 * 4);
  u16*   Qb    = (u16*)  alloc((size_t)32 * 1024 * QKD * 2);
  u16*   Kb    = (u16*)  alloc((size_t)32 * 1024 * QKD * 2);
  u16*   Vt    = (u16*)  alloc((size_t)32 * 64 * 1024 * 2);
  u16*   attn  = (u16*)  alloc((size_t)Mm * 1024 * 2);
  u16*   gate  = (u16*)  alloc((size_t)Mm * 2816 * 2);

  dim3 tb(32, 8);
  auto cvt = [&](const float* src, u16* dst, int K, int N, int Npad) {
    dim3 gg(K / 32, Npad / 32);
    k_wcvt<<<gg, tb, 0, stream>>>(src, dst, K, N, Npad);
  };

  k_embed<<<Mm, 256, 0, stream>>>(tokens, embed, h);

  for (int l = 0; l < 4; l++) {
    cvt(w_kv_down + (size_t)l * 1024 * 288,  wT_dq,            1024, 288, 384);
    cvt(w_q_down  + (size_t)l * 1024 * 384,  wT_dq + 384*1024, 1024, 384, 384);
    cvt(w_kv_up   + (size_t)l * 256 * 2048,  wT_kvup,          256, 2048, 2048);
    cvt(w_q_up    + (size_t)l * 384 * 1536,  wT_qup,           384, 1536, 1536);
    cvt(w_o       + (size_t)l * 1024 * 1024, wT_o,             1024, 1024, 1024);
    k_wcvt_perm<<<dim3(32, 176), tb, 0, stream>>>(w_in + (size_t)l * 1024 * 5632,
                                                  wT_in, 1024);
    cvt(w_out     + (size_t)l * 2816 * 1024, wT_out,           2816, 1024, 1024);
    k_biascat<<<3, 256, 0, stream>>>(b_kv_down + l * 288, b_q_down + l * 384, bdq);

    k_rms<<<Mm, 256, 0, stream>>>(h, 1024, norm1_w + l * 1024, xn, 1024);
    k_gemm<0, 64, true><<<dim3(16, 12), 256, 0, stream>>>(xn, wT_dq, bdq,
                                                          ckvq, 768, 1024, 0, 0, 0);
    k_rms<<<Mm, 256, 0, stream>>>(ckvq, 768, kv_norm_w + l * 256, ckvn, 256);
    k_gemm<0, 128, true><<<dim3(16, 16), 256, 0, stream>>>(ckvn, wT_kvup, b_kv_up + l * 2048,
                                                           kv, 2048, 256, 0, 0, 0);
    k_rms<<<Mm, 256, 0, stream>>>(ckvq + 384, 768, q_norm_w + l * 384, qdn, 384);
    k_gemm<0, 128, true><<<dim3(16, 12), 256, 0, stream>>>(qdn, wT_qup, b_q_up + l * 1536,
                                                           qf, 1536, 384, 0, 0, 0);
    k_buildq<<<dim3(Ss, 32), 128, 0, stream>>>(qf, Qb);
    k_buildk<<<dim3(Ss, 32), 128, 0, stream>>>(kv, ckvq, Kb);
    k_buildvt<<<dim3(32, 32, 2), tb, 0, stream>>>(kv, Vt);
    k_flash<<<dim3(8, 32), 256, 0, stream>>>(Qb, Kb, Vt, attn);
    k_gemm<1, 64, true><<<dim3(16, 16), 256, 0, stream>>>(attn, wT_o, b_o + l * 1024,
                                                          h, 1024, 1024, 0, 0, 0);
    k_rms<<<Mm, 256, 0, stream>>>(h, 1024, norm2_w + l * 1024, xn, 1024);
    // fused w_in + silu: bf16 gate out, grid 176 = 8 x 22
    k_gemm256<1><<<176, 512, 0, stream>>>(xn, wT_in, b_in + l * 5632, gate, 5632, 1024);
    k_gemm<1, 64, true><<<dim3(16, 16), 256, 0, stream>>>(gate, wT_out, b_out + l * 1024,
                                                          h, 1024, 2816, 0, 0, 0);
  }

  k_rms<<<Mm, 256, 0, stream>>>(h, 1024, norm_f_w, xn, 1024);
  cvt(w_head, warena, 1024, 32000, 32000);
  k_gemm256<0><<<1000, 512, 0, stream>>>(xn, warena, b_head, (float*)d_out, 32000, 1024);
}

// Round 6
// 1377.514 us; speedup vs baseline: 1.2806x; 1.0305x over previous
//
#include <hip/hip_runtime.h>
#include <cstdint>
#include <cstddef>

typedef unsigned short u16;
typedef __attribute__((__ext_vector_type__(8))) __bf16 bf16x8;
typedef __attribute__((__ext_vector_type__(4))) float f32x4;
typedef __attribute__((__ext_vector_type__(8))) unsigned short u16x8;

#define DEVI __device__ __forceinline__

constexpr int Bb = 2, Ss = 1024, Dd = 1024, Hh = 16;
constexpr int Mm = Bb * Ss;       // 2048 token rows
constexpr int QKD = 128;          // padded q/k head dim (96 -> 128, zero pad)
constexpr float EPSF = 1.1920929e-07f;
constexpr float NEG = -1e30f;
constexpr float QSCALE = 0.10206207261596577f; // 1/sqrt(96)
constexpr float LOG1E4_16 = 9.210340371976184f / 16.f;

DEVI u16 f2b(float f) {
  union { float f; uint32_t u; } a; a.f = f;
  uint32_t r = a.u + 0x7FFFu + ((a.u >> 16) & 1u);
  return (u16)(r >> 16);
}
DEVI float b2f(u16 h) {
  union { uint32_t u; float f; } a; a.u = ((uint32_t)h) << 16; return a.f;
}

// ---------------- fp32 -> bf16 transposed weight conversion (K x N -> Npad x K)
__global__ void k_wcvt(const float* __restrict__ in, u16* __restrict__ out,
                       int K, int N, int Npad) {
  __shared__ float t[32][33];
  int bk = blockIdx.x * 32, bn = blockIdx.y * 32;
  int tx = threadIdx.x, ty = threadIdx.y;
  #pragma unroll
  for (int i = ty; i < 32; i += 8) {
    int n = bn + tx;
    t[i][tx] = (n < N) ? in[(size_t)(bk + i) * N + n] : 0.f;
  }
  __syncthreads();
  #pragma unroll
  for (int i = ty; i < 32; i += 8) {
    int n = bn + i;
    out[(size_t)n * K + bk + tx] = f2b(t[tx][i]);
  }
}

// ---------------- fp32 -> bf16 transpose for w_in with u/x pair interleave:
// out row n <- src col (n odd ? n/2 + 2816 : n/2)
__global__ void k_wcvt_perm(const float* __restrict__ in, u16* __restrict__ out,
                            int K) {
  __shared__ float t[32][33];
  int bk = blockIdx.x * 32, bn = blockIdx.y * 32;
  int tx = threadIdx.x, ty = threadIdx.y;
  #pragma unroll
  for (int i = ty; i < 32; i += 8) {
    int n = bn + tx;
    int src = (n & 1) ? (n >> 1) + 2816 : (n >> 1);
    t[i][tx] = in[(size_t)(bk + i) * 5632 + src];
  }
  __syncthreads();
  #pragma unroll
  for (int i = ty; i < 32; i += 8) {
    int n = bn + i;
    out[(size_t)n * K + bk + tx] = f2b(t[tx][i]);
  }
}

// ---------------- embedding gather
__global__ void k_embed(const int* __restrict__ tok, const float* __restrict__ emb,
                        float* __restrict__ h) {
  int m = blockIdx.x;
  int t = tok[m];
  const float4* src = (const float4*)(emb + (size_t)t * Dd);
  float4* dst = (float4*)(h + (size_t)m * Dd);
  dst[threadIdx.x] = src[threadIdx.x];
}

// ---------------- rmsnorm: f32 (stride inStride) -> bf16 (stride K)
__global__ void k_rms(const float* __restrict__ in, int inStride,
                      const float* __restrict__ w, u16* __restrict__ out, int K) {
  int m = blockIdx.x;
  const float* x = in + (size_t)m * inStride;
  float ss = 0.f;
  for (int i = threadIdx.x; i < K; i += 256) { float v = x[i]; ss += v * v; }
  #pragma unroll
  for (int off = 32; off; off >>= 1) ss += __shfl_xor(ss, off);
  __shared__ float red[4];
  if ((threadIdx.x & 63) == 0) red[threadIdx.x >> 6] = ss;
  __syncthreads();
  float r = rsqrtf((red[0] + red[1] + red[2] + red[3]) / (float)K + EPSF);
  for (int i = threadIdx.x; i < K; i += 256)
    out[(size_t)m * K + i] = f2b(x[i] * r * w[i]);
}

// ---------------- bias concat for fused down-proj (288 kv | pad | 384 q)
__global__ void k_biascat(const float* __restrict__ b1, const float* __restrict__ b2,
                          float* __restrict__ out) {
  int i = blockIdx.x * 256 + threadIdx.x;  // 0..767
  float v = 0.f;
  if (i < 288) v = b1[i];
  else if (i >= 384) v = b2[i - 384];
  out[i] = v;
}

// ---------------- build Q (rope on cols 64..95, *QSCALE, pad to 128)
__global__ void k_buildq(const float* __restrict__ qf, u16* __restrict__ Q) {
  int s = blockIdx.x, bh = blockIdx.y;
  int b = bh >> 4, h = bh & 15;
  int d = threadIdx.x;
  const float* row = qf + (size_t)(b * Ss + s) * (Hh * 96) + h * 96;
  float v = 0.f;
  if (d < 64) v = row[d];
  else if (d < 96) {
    int j = d - 64;
    int jj = j & 15;
    float theta = __expf(-(float)jj * LOG1E4_16);
    float ang = (float)s * theta;
    float sn, cs; __sincosf(ang, &sn, &cs);
    float x = row[64 + j];
    float o = row[64 + (j ^ 16)];
    v = x * cs + ((j < 16) ? -o : o) * sn;
  }
  Q[((size_t)bh * Ss + s) * QKD + d] = f2b(v * QSCALE);
}

// ---------------- build K (k from kv, roped k_rope from fused ckvq, bcast over heads)
__global__ void k_buildk(const float* __restrict__ kv, const float* __restrict__ ckvq,
                         u16* __restrict__ Kb) {
  int s = blockIdx.x, bh = blockIdx.y;
  int b = bh >> 4, h = bh & 15;
  int d = threadIdx.x;
  int m = b * Ss + s;
  float v = 0.f;
  if (d < 64) v = kv[(size_t)m * 2048 + h * 128 + d];
  else if (d < 96) {
    int j = d - 64;
    int jj = j & 15;
    float theta = __expf(-(float)jj * LOG1E4_16);
    float ang = (float)s * theta;
    float sn, cs; __sincosf(ang, &sn, &cs);
    const float* rr = ckvq + (size_t)m * 768 + 256;
    float x = rr[j];
    float o = rr[j ^ 16];
    v = x * cs + ((j < 16) ? -o : o) * sn;
  }
  Kb[((size_t)bh * Ss + s) * QKD + d] = f2b(v);
}

// ---------------- build V^T (per head: [64][1024]), bf16
__global__ void k_buildvt(const float* __restrict__ kv, u16* __restrict__ Vt) {
  __shared__ float t[32][33];
  int bh = blockIdx.x, s0 = blockIdx.y * 32, d0 = blockIdx.z * 32;
  int b = bh >> 4, h = bh & 15;
  int tx = threadIdx.x, ty = threadIdx.y;
  #pragma unroll
  for (int i = ty; i < 32; i += 8) {
    int s = s0 + i, d = d0 + tx;
    t[i][tx] = kv[(size_t)(b * Ss + s) * 2048 + h * 128 + 64 + d];
  }
  __syncthreads();
  #pragma unroll
  for (int i = ty; i < 32; i += 8) {
    int d = d0 + i, s = s0 + tx;
    Vt[((size_t)bh * 64 + d) * Ss + s] = f2b(t[tx][i]);
  }
}

#define GAS __attribute__((address_space(1)))
#define LAS __attribute__((address_space(3)))
DEVI void gll16(const void* g, void* l) {
  __builtin_amdgcn_global_load_lds((GAS const void*)g, (LAS void*)l, 16, 0, 0);
}

// ---------------- fused flash attention (causal), bf16 in/out
__global__ __launch_bounds__(256) void k_flash(
    const u16* __restrict__ Qg, const u16* __restrict__ Kg,
    const u16* __restrict__ Vtg, u16* __restrict__ attn) {
  __shared__ u16 lK[64 * 128];
  __shared__ u16 lV[64 * 64];
  __shared__ u16 lP[4][16 * 64];
  const int tid = threadIdx.x;
  const int pair = blockIdx.x, bh = blockIdx.y;
  const int b = bh >> 4, h = bh & 15;
  const int lane = tid & 63, w = tid >> 6;
  const int g = lane >> 4, fr = lane & 15;
  const u16* Qh = Qg + (size_t)bh * Ss * QKD;
  const u16* Kh = Kg + (size_t)bh * Ss * QKD;
  const u16* Vh = Vtg + (size_t)bh * 64 * Ss;

  for (int pass = 0; pass < 2; ++pass) {
    const int qt = pass ? (15 - pair) : pair;
    const int q0 = qt * 64;
    bf16x8 af[4];
    const u16* qrow = Qh + (size_t)(q0 + w * 16 + fr) * QKD + g * 8;
    #pragma unroll
    for (int k4 = 0; k4 < 4; ++k4) af[k4] = *(const bf16x8*)(qrow + k4 * 32);

    f32x4 acc_o[4] = {};
    float mrow = NEG, lrow = 0.f;

    for (int kt = 0; kt <= qt; ++kt) {
      {
        int r = tid >> 4, c = tid & 15;
        #pragma unroll
        for (int gg = 0; gg < 4; ++gg) {
          int row = gg * 16 + r;
          const u16* src = Kh + (size_t)(kt * 64 + row) * QKD + ((c ^ (row & 7)) * 8);
          gll16(src, (u16*)lK + gg * 2048 + tid * 8);
        }
        int r2 = tid >> 3, c2 = tid & 7;
        #pragma unroll
        for (int gg = 0; gg < 2; ++gg) {
          int d = gg * 32 + r2;
          const u16* src = Vh + (size_t)d * Ss + kt * 64 + ((c2 ^ (d & 7)) * 8);
          gll16(src, (u16*)lV + gg * 2048 + tid * 8);
        }
      }
      asm volatile("s_waitcnt vmcnt(0)" ::: "memory");
      __builtin_amdgcn_s_barrier();
      asm volatile("" ::: "memory");

      f32x4 accs[4] = {};
      #pragma unroll
      for (int j = 0; j < 4; ++j) {
        #pragma unroll
        for (int k4 = 0; k4 < 4; ++k4) {
          int row = j * 16 + fr;
          int ch = (k4 * 4 + g) ^ (row & 7);
          bf16x8 kf = *(const bf16x8*)&lK[row * 128 + ch * 8];
          accs[j] = __builtin_amdgcn_mfma_f32_16x16x32_bf16(kf, af[k4], accs[j], 0, 0, 0);
        }
      }

      float p[16];
      float tmax = NEG;
      #pragma unroll
      for (int j = 0; j < 4; ++j)
        #pragma unroll
        for (int r = 0; r < 4; ++r) {
          float s = accs[j][r];
          int kloc = j * 16 + 4 * g + r;
          bool valid = (kt < qt) || (kloc <= w * 16 + fr);
          s = valid ? s : NEG;
          p[j * 4 + r] = s;
          tmax = fmaxf(tmax, s);
        }
      tmax = fmaxf(tmax, __shfl_xor(tmax, 16));
      tmax = fmaxf(tmax, __shfl_xor(tmax, 32));
      float mnew = fmaxf(mrow, tmax);
      float scale = __expf(mrow - mnew);
      float tsum = 0.f;
      #pragma unroll
      for (int i = 0; i < 16; ++i) { p[i] = __expf(p[i] - mnew); tsum += p[i]; }
      tsum += __shfl_xor(tsum, 16);
      tsum += __shfl_xor(tsum, 32);
      lrow = lrow * scale + tsum;
      mrow = mnew;

      #pragma unroll
      for (int j = 0; j < 4; ++j)
        #pragma unroll
        for (int t = 0; t < 2; ++t) {
          uint32_t u = (uint32_t)f2b(p[j * 4 + 2 * t]) |
                       ((uint32_t)f2b(p[j * 4 + 2 * t + 1]) << 16);
          int kp = 8 * j + 2 * g + t;
          int ch = kp >> 2, wi = kp & 3;
          ((uint32_t*)lP[w])[fr * 32 + ((ch ^ (fr & 7)) << 2) + wi] = u;
        }

      float sc_q[4];
      #pragma unroll
      for (int r = 0; r < 4; ++r) sc_q[r] = __shfl(scale, 4 * g + r);
      #pragma unroll
      for (int j2 = 0; j2 < 4; ++j2)
        #pragma unroll
        for (int r = 0; r < 4; ++r) acc_o[j2][r] *= sc_q[r];

      #pragma unroll
      for (int ksub = 0; ksub < 2; ++ksub) {
        int chp = (4 * ksub + g) ^ (fr & 7);
        bf16x8 pa = *(const bf16x8*)&((const u16*)lP[w])[fr * 64 + chp * 8];
        #pragma unroll
        for (int j2 = 0; j2 < 4; ++j2) {
          int d = j2 * 16 + fr;
          int chv = (ksub * 4 + g) ^ (d & 7);
          bf16x8 vf = *(const bf16x8*)&lV[d * 64 + chv * 8];
          acc_o[j2] = __builtin_amdgcn_mfma_f32_16x16x32_bf16(pa, vf, acc_o[j2], 0, 0, 0);
        }
      }
      asm volatile("" ::: "memory");
      __builtin_amdgcn_s_barrier();
      asm volatile("" ::: "memory");
    }

    float li[4];
    #pragma unroll
    for (int r = 0; r < 4; ++r) li[r] = 1.f / __shfl(lrow, 4 * g + r);
    #pragma unroll
    for (int j2 = 0; j2 < 4; ++j2)
      #pragma unroll
      for (int r = 0; r < 4; ++r) {
        int q = q0 + w * 16 + 4 * g + r;
        int d = j2 * 16 + fr;
        attn[((size_t)(b * Ss) + q) * Dd + h * 64 + d] = f2b(acc_o[j2][r] * li[r]);
      }
  }
}

// ---------------- 128x256xK GEMM, BK=32, 8 waves (2Mx4N, 64x64/wave),
// 24KB LDS, 2 blocks/CU (TLP hides stage+barrier). Chunk-XOR swizzle:
// element (r, c) stored at chunk (c>>3) ^ ((r>>1)&3)  -> conflict-free b128.
// MODE 0: f32 C = acc + bias
// MODE 1: silu-fused (pair-interleaved Bt): bf16 gate out [M][2816]
template <int MODE>
__global__ __launch_bounds__(512, 4) void k_gemm256b(
    const u16* __restrict__ A, const u16* __restrict__ Bt,
    const float* __restrict__ bias, void* __restrict__ Cv,
    int N, int K) {
  __shared__ u16 lA[128 * 32];
  __shared__ u16 lB[256 * 32];
  const int tid = threadIdx.x;
  const int gx = gridDim.x;
  const int nwg = gx * gridDim.y;
  const int f = blockIdx.y * gx + blockIdx.x;
  const int f2 = (f & 7) * (nwg >> 3) + (f >> 3);   // xcd swizzle (nwg % 8 == 0)
  const int bx = f2 % gx, by = f2 / gx;
  const long m0 = (long)bx * 128, n0 = (long)by * 256;
  const int lane = tid & 63, wid = tid >> 6;
  const int wm = (wid >> 2) * 64, wn = (wid & 3) * 64;
  const int fr = lane & 15, l4 = lane >> 4;
  const int sw = (fr >> 1) & 3;

  const int ra = tid >> 2;                      // A stage row 0..127
  const int ca = ((tid & 3) ^ ((ra >> 1) & 3)) * 8;
  const u16* a0 = A + (m0 + ra) * (long)K + ca;
  const int rb = tid >> 2;                      // B stage rows rb, rb+128
  const int cb0 = ((tid & 3) ^ ((rb >> 1) & 3)) * 8;
  const int cb1 = ((tid & 3) ^ (((rb + 128) >> 1) & 3)) * 8;
  const u16* b0 = Bt + (n0 + rb) * (long)K + cb0;
  const u16* b1 = Bt + (n0 + rb + 128) * (long)K + cb1;

  f32x4 acc[4][4] = {};

  for (int kk = 0; kk < K; kk += 32) {
    gll16(a0 + kk, (u16*)lA + tid * 8);
    gll16(b0 + kk, (u16*)lB + tid * 8);
    gll16(b1 + kk, (u16*)lB + 4096 + tid * 8);
    __syncthreads();
    bf16x8 af[4], bf[4];
    #pragma unroll
    for (int i = 0; i < 4; ++i)
      af[i] = *(const bf16x8*)&lA[(wm + i * 16 + fr) * 32 + ((l4 ^ sw) * 8)];
    #pragma unroll
    for (int j = 0; j < 4; ++j)
      bf[j] = *(const bf16x8*)&lB[(wn + j * 16 + fr) * 32 + ((l4 ^ sw) * 8)];
    #pragma unroll
    for (int i = 0; i < 4; ++i)
      #pragma unroll
      for (int j = 0; j < 4; ++j)
        acc[i][j] = __builtin_amdgcn_mfma_f32_16x16x32_bf16(af[i], bf[j], acc[i][j], 0, 0, 0);
    __syncthreads();
  }

  const long r0 = m0 + wm + l4 * 4;
  const long c0 = n0 + wn + fr;
  if (MODE == 0) {
    float* C = (float*)Cv;
    #pragma unroll
    for (int j = 0; j < 4; ++j) {
      long col = c0 + j * 16;
      float bs = bias[col];
      #pragma unroll
      for (int i = 0; i < 4; ++i)
        #pragma unroll
        for (int r = 0; r < 4; ++r)
          C[(r0 + i * 16 + r) * (long)N + col] = acc[i][j][r] + bs;
    }
  } else {
    u16* G = (u16*)Cv;
    #pragma unroll
    for (int j = 0; j < 4; ++j) {
      long col = c0 + j * 16;
      int pcol = (int)((col & 1) ? (col >> 1) + 2816 : (col >> 1));
      float bs = bias[pcol];
      #pragma unroll
      for (int i = 0; i < 4; ++i)
        #pragma unroll
        for (int r = 0; r < 4; ++r) {
          float val = acc[i][j][r] + bs;
          float oth = __shfl_xor(val, 1);
          if (!(col & 1)) {
            float x = oth;
            float gv = val * x * (1.f / (1.f + __expf(-x)));
            G[(r0 + i * 16 + r) * 2816L + (col >> 1)] = f2b(gv);
          }
        }
    }
  }
}

// ---------------- bf16 MFMA GEMM 128xBN (m97 structure)
// MODE 0: f32 C = acc + bias ; MODE 1: f32 C += acc + bias
template <int MODE, int BN, bool SWZ>
__global__ __launch_bounds__(256) void k_gemm(
    const u16* __restrict__ A, const u16* __restrict__ Bt,
    const float* __restrict__ bias, void* __restrict__ C,
    int N, int K, long sA, long sB, long sC) {
  __shared__ u16 lA[128 * 32];
  __shared__ u16 lB[BN * 32];
  const int tid = threadIdx.x;
  const int bz = blockIdx.z;

  int bx, by;
  if (SWZ) {
    int gx = gridDim.x;
    int nwg = gx * gridDim.y;
    int f = blockIdx.y * gx + blockIdx.x;
    int f2 = (f & 7) * (nwg >> 3) + (f >> 3);
    bx = f2 % gx; by = f2 / gx;
  } else {
    bx = blockIdx.x; by = blockIdx.y;
  }
  const long m0 = (long)bx * 128, n0 = (long)by * BN;

  const u16* Az = A + (size_t)bz * sA;
  const u16* Bz = Bt + (size_t)bz * sB;
  const int srow = tid >> 2;
  const int scol = (tid & 3) << 3;
  const u16* a0 = Az + (m0 + srow) * (long)K + scol;
  const u16* b0 = Bz + (n0 + srow) * (long)K + scol;
  const long rstep = 64L * K;

  const int lane = tid & 63, wid = tid >> 6;
  constexpr int WR = (BN == 128) ? 64 : 32;
  constexpr int MI = WR / 16;
  const int wm = (BN == 128) ? (wid >> 1) * 64 : wid * 32;
  const int wn = (BN == 128) ? (wid & 1) * 64 : 0;
  const int fr = lane & 15, kg = (lane >> 4) * 8;

  f32x4 acc[MI][4] = {};

  for (int kk = 0; kk < K; kk += 32) {
    gll16(a0 + kk, lA + tid * 8);
    gll16(a0 + rstep + kk, lA + 2048 + tid * 8);
    gll16(b0 + kk, lB + tid * 8);
    if (BN == 128) gll16(b0 + rstep + kk, lB + 2048 + tid * 8);
    __syncthreads();
    bf16x8 af[MI], bfr[4];
    #pragma unroll
    for (int i = 0; i < MI; i++) af[i] = *(const bf16x8*)&lA[(wm + i * 16 + fr) * 32 + kg];
    #pragma unroll
    for (int j = 0; j < 4; j++) bfr[j] = *(const bf16x8*)&lB[(wn + j * 16 + fr) * 32 + kg];
    #pragma unroll
    for (int i = 0; i < MI; i++)
      #pragma unroll
      for (int j = 0; j < 4; j++)
        acc[i][j] = __builtin_amdgcn_mfma_f32_16x16x32_bf16(af[i], bfr[j], acc[i][j], 0, 0, 0);
    __syncthreads();
  }

  const int rb = wm + ((lane >> 4) << 2);
  const int cb = wn + (lane & 15);
  #pragma unroll
  for (int j = 0; j < 4; j++) {
    long gcol = n0 + cb + j * 16;
    float bs = 0.f;
    if (gcol < N) bs = bias[gcol];
    #pragma unroll
    for (int i = 0; i < MI; i++) {
      #pragma unroll
      for (int r = 0; r < 4; r++) {
        long grow = m0 + rb + i * 16 + r;
        float val = acc[i][j][r];
        if (MODE == 0) {
          if (gcol < N) ((float*)C)[grow * N + gcol] = val + bs;
        } else {
          if (gcol < N) { float* p = (float*)C + grow * N + gcol; *p += val + bs; }
        }
      }
    }
  }
}

extern "C" void kernel_launch(void* const* d_in, const int* in_sizes, int n_in,
                              void* d_out, int out_size, void* d_ws, size_t ws_size,
                              hipStream_t stream) {
  (void)in_sizes; (void)n_in; (void)out_size; (void)ws_size;
  const int*   tokens    = (const int*)  d_in[0];
  const float* embed     = (const float*)d_in[1];
  const float* w_kv_down = (const float*)d_in[2];
  const float* b_kv_down = (const float*)d_in[3];
  const float* w_q_down  = (const float*)d_in[4];
  const float* b_q_down  = (const float*)d_in[5];
  const float* w_kv_up   = (const float*)d_in[6];
  const float* b_kv_up   = (const float*)d_in[7];
  const float* w_q_up    = (const float*)d_in[8];
  const float* b_q_up    = (const float*)d_in[9];
  const float* w_o       = (const float*)d_in[10];
  const float* b_o       = (const float*)d_in[11];
  const float* kv_norm_w = (const float*)d_in[12];
  const float* q_norm_w  = (const float*)d_in[13];
  const float* norm1_w   = (const float*)d_in[14];
  const float* norm2_w   = (const float*)d_in[15];
  const float* w_in      = (const float*)d_in[16];
  const float* b_in      = (const float*)d_in[17];
  const float* w_out     = (const float*)d_in[18];
  const float* b_out     = (const float*)d_in[19];
  const float* norm_f_w  = (const float*)d_in[20];
  const float* w_head    = (const float*)d_in[21];
  const float* b_head    = (const float*)d_in[22];

  char* base = (char*)d_ws;
  size_t off = 0;
  auto alloc = [&](size_t bytes) -> void* {
    void* p = base + off;
    off += (bytes + 255) & ~(size_t)255;
    return p;
  };
  u16* warena = (u16*)alloc((size_t)32000 * 1024 * 2);
  u16* wT_dq    = warena;                        // 768 x 1024
  u16* wT_kvup  = wT_dq   + 768 * 1024;          // 2048 x 256
  u16* wT_qup   = wT_kvup + 2048 * 256;          // 1536 x 384
  u16* wT_o     = wT_qup  + 1536 * 384;          // 1024 x 1024
  u16* wT_in    = wT_o    + 1024 * 1024;         // 5632 x 1024 (pair-interleaved)
  u16* wT_out   = wT_in   + 5632 * 1024;         // 1024 x 2816

  float* h     = (float*)alloc((size_t)Mm * 1024 * 4);
  u16*   xn    = (u16*)  alloc((size_t)Mm * 1024 * 2);
  float* ckvq  = (float*)alloc((size_t)Mm * 768 * 4);
  float* bdq   = (float*)alloc(768 * 4);
  u16*   ckvn  = (u16*)  alloc((size_t)Mm * 256 * 2);
  float* kv    = (float*)alloc((size_t)Mm * 2048 * 4);
  u16*   qdn   = (u16*)  alloc((size_t)Mm * 384 * 2);
  float* qf    = (float*)alloc((size_t)Mm * 1536 * 4);
  u16*   Qb    = (u16*)  alloc((size_t)32 * 1024 * QKD * 2);
  u16*   Kb    = (u16*)  alloc((size_t)32 * 1024 * QKD * 2);
  u16*   Vt    = (u16*)  alloc((size_t)32 * 64 * 1024 * 2);
  u16*   attn  = (u16*)  alloc((size_t)Mm * 1024 * 2);
  u16*   gate  = (u16*)  alloc((size_t)Mm * 2816 * 2);

  dim3 tb(32, 8);
  auto cvt = [&](const float* src, u16* dst, int K, int N, int Npad) {
    dim3 gg(K / 32, Npad / 32);
    k_wcvt<<<gg, tb, 0, stream>>>(src, dst, K, N, Npad);
  };

  k_embed<<<Mm, 256, 0, stream>>>(tokens, embed, h);

  for (int l = 0; l < 4; l++) {
    cvt(w_kv_down + (size_t)l * 1024 * 288,  wT_dq,            1024, 288, 384);
    cvt(w_q_down  + (size_t)l * 1024 * 384,  wT_dq + 384*1024, 1024, 384, 384);
    cvt(w_kv_up   + (size_t)l * 256 * 2048,  wT_kvup,          256, 2048, 2048);
    cvt(w_q_up    + (size_t)l * 384 * 1536,  wT_qup,           384, 1536, 1536);
    cvt(w_o       + (size_t)l * 1024 * 1024, wT_o,             1024, 1024, 1024);
    k_wcvt_perm<<<dim3(32, 176), tb, 0, stream>>>(w_in + (size_t)l * 1024 * 5632,
                                                  wT_in, 1024);
    cvt(w_out     + (size_t)l * 2816 * 1024, wT_out,           2816, 1024, 1024);
    k_biascat<<<3, 256, 0, stream>>>(b_kv_down + l * 288, b_q_down + l * 384, bdq);

    k_rms<<<Mm, 256, 0, stream>>>(h, 1024, norm1_w + l * 1024, xn, 1024);
    k_gemm<0, 64, true><<<dim3(16, 12), 256, 0, stream>>>(xn, wT_dq, bdq,
                                                          ckvq, 768, 1024, 0, 0, 0);
    k_rms<<<Mm, 256, 0, stream>>>(ckvq, 768, kv_norm_w + l * 256, ckvn, 256);
    k_gemm<0, 128, true><<<dim3(16, 16), 256, 0, stream>>>(ckvn, wT_kvup, b_kv_up + l * 2048,
                                                           kv, 2048, 256, 0, 0, 0);
    k_rms<<<Mm, 256, 0, stream>>>(ckvq + 384, 768, q_norm_w + l * 384, qdn, 384);
    k_gemm<0, 128, true><<<dim3(16, 12), 256, 0, stream>>>(qdn, wT_qup, b_q_up + l * 1536,
                                                           qf, 1536, 384, 0, 0, 0);
    k_buildq<<<dim3(Ss, 32), 128, 0, stream>>>(qf, Qb);
    k_buildk<<<dim3(Ss, 32), 128, 0, stream>>>(kv, ckvq, Kb);
    k_buildvt<<<dim3(32, 32, 2), tb, 0, stream>>>(kv, Vt);
    k_flash<<<dim3(8, 32), 256, 0, stream>>>(Qb, Kb, Vt, attn);
    k_gemm<1, 64, true><<<dim3(16, 16), 256, 0, stream>>>(attn, wT_o, b_o + l * 1024,
                                                          h, 1024, 1024, 0, 0, 0);
    k_rms<<<Mm, 256, 0, stream>>>(h, 1024, norm2_w + l * 1024, xn, 1024);
    // fused w_in + silu: 128x256 tile, grid 16 x 22 = 352 blocks
    k_gemm256b<1><<<dim3(16, 22), 512, 0, stream>>>(xn, wT_in, b_in + l * 5632,
                                                    gate, 5632, 1024);
    k_gemm<1, 64, true><<<dim3(16, 16), 256, 0, stream>>>(gate, wT_out, b_out + l * 1024,
                                                          h, 1024, 2816, 0, 0, 0);
  }

  k_rms<<<Mm, 256, 0, stream>>>(h, 1024, norm_f_w, xn, 1024);
  cvt(w_head, warena, 1024, 32000, 32000);
  // head: 128x256 tile, grid 16 x 125 = 2000 blocks
  k_gemm256b<0><<<dim3(16, 125), 512, 0, stream>>>(xn, warena, b_head,
                                                   (float*)d_out, 32000, 1024);
}

// Round 7
// 1204.688 us; speedup vs baseline: 1.4643x; 1.1435x over previous
//
#include <hip/hip_runtime.h>
#include <cstdint>
#include <cstddef>

typedef unsigned short u16;
typedef __attribute__((__ext_vector_type__(8))) __bf16 bf16x8;
typedef __attribute__((__ext_vector_type__(4))) float f32x4;
typedef __attribute__((__ext_vector_type__(8))) unsigned short u16x8;

#define DEVI __device__ __forceinline__

constexpr int Bb = 2, Ss = 1024, Dd = 1024, Hh = 16;
constexpr int Mm = Bb * Ss;       // 2048 token rows
constexpr int QKD = 128;          // padded q/k head dim (96 -> 128, zero pad)
constexpr float EPSF = 1.1920929e-07f;
constexpr float NEG = -1e30f;
constexpr float QSCALE = 0.10206207261596577f; // 1/sqrt(96)
constexpr float LOG1E4_16 = 9.210340371976184f / 16.f;

DEVI u16 f2b(float f) {
  union { float f; uint32_t u; } a; a.f = f;
  uint32_t r = a.u + 0x7FFFu + ((a.u >> 16) & 1u);
  return (u16)(r >> 16);
}
DEVI float b2f(u16 h) {
  union { uint32_t u; float f; } a; a.u = ((uint32_t)h) << 16; return a.f;
}

// ---------------- batched fp32 -> bf16 transposed weight conversion
// Each job: src [K][N] f32 row-major -> dst [Nrows][K] bf16 (Nrows = tiles*64/K... via ntiles)
// perm=1 (w_in): src col c -> dst row (c<2816 ? 2c : 2(c-2816)+1)  [pair interleave]
// Tiles are 64(K) x 64(N); cols >= N read as 0 (pad rows written zero).
struct WJob { const float* src; u16* dst; int K; int N; int perm; int ntiles; };
struct WJobs { WJob j[7]; };

__global__ __launch_bounds__(256) void k_wcvt_batch(WJobs jobs, int njobs) {
  int t = blockIdx.x;
  int ji = 0;
  while (ji < njobs - 1 && t >= jobs.j[ji].ntiles) { t -= jobs.j[ji].ntiles; ++ji; }
  const float* __restrict__ src = jobs.j[ji].src;
  u16* __restrict__ dst = jobs.j[ji].dst;
  const int K = jobs.j[ji].K, N = jobs.j[ji].N, perm = jobs.j[ji].perm;
  const int ktiles = K >> 6;
  const int bk = (t % ktiles) * 64;
  const int bn = (t / ktiles) * 64;
  __shared__ float ts[64][65];
  const int tid = threadIdx.x;
  {
    int c4 = tid & 15, r = tid >> 4;
    #pragma unroll
    for (int p = 0; p < 4; ++p) {
      int row = r + p * 16;
      int col = bn + c4 * 4;
      float4 v = make_float4(0.f, 0.f, 0.f, 0.f);
      if (col < N) v = *(const float4*)(src + (size_t)(bk + row) * N + col);
      ts[row][c4 * 4 + 0] = v.x; ts[row][c4 * 4 + 1] = v.y;
      ts[row][c4 * 4 + 2] = v.z; ts[row][c4 * 4 + 3] = v.w;
    }
  }
  __syncthreads();
  {
    int k8 = tid & 7, c = tid >> 3;   // 32 cols per pass
    #pragma unroll
    for (int p = 0; p < 2; ++p) {
      int cc = c + p * 32;
      int gcol = bn + cc;
      int row = perm ? ((gcol < 2816) ? (gcol * 2) : ((gcol - 2816) * 2 + 1)) : gcol;
      u16x8 o;
      #pragma unroll
      for (int q = 0; q < 8; ++q) o[q] = f2b(ts[k8 * 8 + q][cc]);
      *(u16x8*)(dst + (size_t)row * K + bk + k8 * 8) = o;
    }
  }
}

// ---------------- embedding gather
__global__ void k_embed(const int* __restrict__ tok, const float* __restrict__ emb,
                        float* __restrict__ h) {
  int m = blockIdx.x;
  int t = tok[m];
  const float4* src = (const float4*)(emb + (size_t)t * Dd);
  float4* dst = (float4*)(h + (size_t)m * Dd);
  dst[threadIdx.x] = src[threadIdx.x];
}

// ---------------- rmsnorm: f32 (stride inStride) -> bf16 (stride K)
__global__ void k_rms(const float* __restrict__ in, int inStride,
                      const float* __restrict__ w, u16* __restrict__ out, int K) {
  int m = blockIdx.x;
  const float* x = in + (size_t)m * inStride;
  float ss = 0.f;
  for (int i = threadIdx.x; i < K; i += 256) { float v = x[i]; ss += v * v; }
  #pragma unroll
  for (int off = 32; off; off >>= 1) ss += __shfl_xor(ss, off);
  __shared__ float red[4];
  if ((threadIdx.x & 63) == 0) red[threadIdx.x >> 6] = ss;
  __syncthreads();
  float r = rsqrtf((red[0] + red[1] + red[2] + red[3]) / (float)K + EPSF);
  for (int i = threadIdx.x; i < K; i += 256)
    out[(size_t)m * K + i] = f2b(x[i] * r * w[i]);
}

// ---------------- bias concat for fused down-proj (288 kv | pad | 384 q)
__global__ void k_biascat(const float* __restrict__ b1, const float* __restrict__ b2,
                          float* __restrict__ out) {
  int i = blockIdx.x * 256 + threadIdx.x;  // 0..767
  float v = 0.f;
  if (i < 288) v = b1[i];
  else if (i >= 384) v = b2[i - 384];
  out[i] = v;
}

// ---------------- build Q and K (rope cols 64..95; Q scaled; pad to 128)
__global__ void k_buildqk(const float* __restrict__ qf, const float* __restrict__ kv,
                          const float* __restrict__ ckvq, u16* __restrict__ Q,
                          u16* __restrict__ Kb) {
  int s = blockIdx.x, bh = blockIdx.y;
  int b = bh >> 4, h = bh & 15;
  int d = threadIdx.x;   // 0..127
  int m = b * Ss + s;
  int j = d - 64;
  float sn = 0.f, cs = 0.f;
  if (d >= 64 && d < 96) {
    float theta = __expf(-(float)(j & 15) * LOG1E4_16);
    __sincosf((float)s * theta, &sn, &cs);
  }
  const float* qrow = qf + (size_t)m * (Hh * 96) + h * 96;
  float qv = 0.f;
  if (d < 64) qv = qrow[d];
  else if (d < 96) {
    float x = qrow[64 + j], o = qrow[64 + (j ^ 16)];
    qv = x * cs + ((j < 16) ? -o : o) * sn;
  }
  Q[((size_t)bh * Ss + s) * QKD + d] = f2b(qv * QSCALE);
  float kvv = 0.f;
  if (d < 64) kvv = kv[(size_t)m * 2048 + h * 128 + d];
  else if (d < 96) {
    const float* rr = ckvq + (size_t)m * 768 + 256;
    float x = rr[j], o = rr[j ^ 16];
    kvv = x * cs + ((j < 16) ? -o : o) * sn;
  }
  Kb[((size_t)bh * Ss + s) * QKD + d] = f2b(kvv);
}

// ---------------- build V^T (per head: [64][1024]), bf16
__global__ void k_buildvt(const float* __restrict__ kv, u16* __restrict__ Vt) {
  __shared__ float t[32][33];
  int bh = blockIdx.x, s0 = blockIdx.y * 32, d0 = blockIdx.z * 32;
  int b = bh >> 4, h = bh & 15;
  int tx = threadIdx.x, ty = threadIdx.y;
  #pragma unroll
  for (int i = ty; i < 32; i += 8) {
    int s = s0 + i, d = d0 + tx;
    t[i][tx] = kv[(size_t)(b * Ss + s) * 2048 + h * 128 + 64 + d];
  }
  __syncthreads();
  #pragma unroll
  for (int i = ty; i < 32; i += 8) {
    int d = d0 + i, s = s0 + tx;
    Vt[((size_t)bh * 64 + d) * Ss + s] = f2b(t[tx][i]);
  }
}

#define GAS __attribute__((address_space(1)))
#define LAS __attribute__((address_space(3)))
DEVI void gll16(const void* g, void* l) {
  __builtin_amdgcn_global_load_lds((GAS const void*)g, (LAS void*)l, 16, 0, 0);
}
#define VMW(n) asm volatile("s_waitcnt vmcnt(" #n ")" ::: "memory")

// ---------------- fused flash attention (causal), bf16 in/out
// grid (16 q-tiles, 32 bh), 256 thr (4 waves). One 64-row q-tile per block.
__global__ __launch_bounds__(256) void k_flash(
    const u16* __restrict__ Qg, const u16* __restrict__ Kg,
    const u16* __restrict__ Vtg, u16* __restrict__ attn) {
  __shared__ u16 lK[64 * 128];
  __shared__ u16 lV[64 * 64];
  __shared__ u16 lP[4][16 * 64];
  const int tid = threadIdx.x;
  const int qt = blockIdx.x, bh = blockIdx.y;
  const int b = bh >> 4, h = bh & 15;
  const int lane = tid & 63, w = tid >> 6;
  const int g = lane >> 4, fr = lane & 15;
  const u16* Qh = Qg + (size_t)bh * Ss * QKD;
  const u16* Kh = Kg + (size_t)bh * Ss * QKD;
  const u16* Vh = Vtg + (size_t)bh * 64 * Ss;

  const int q0 = qt * 64;
  bf16x8 af[4];
  const u16* qrow = Qh + (size_t)(q0 + w * 16 + fr) * QKD + g * 8;
  #pragma unroll
  for (int k4 = 0; k4 < 4; ++k4) af[k4] = *(const bf16x8*)(qrow + k4 * 32);

  f32x4 acc_o[4] = {};
  float mrow = NEG, lrow = 0.f;

  for (int kt = 0; kt <= qt; ++kt) {
    {
      int r = tid >> 4, c = tid & 15;
      #pragma unroll
      for (int gg = 0; gg < 4; ++gg) {
        int row = gg * 16 + r;
        const u16* src = Kh + (size_t)(kt * 64 + row) * QKD + ((c ^ (row & 7)) * 8);
        gll16(src, (u16*)lK + gg * 2048 + tid * 8);
      }
      int r2 = tid >> 3, c2 = tid & 7;
      #pragma unroll
      for (int gg = 0; gg < 2; ++gg) {
        int d = gg * 32 + r2;
        const u16* src = Vh + (size_t)d * Ss + kt * 64 + ((c2 ^ (d & 7)) * 8);
        gll16(src, (u16*)lV + gg * 2048 + tid * 8);
      }
    }
    asm volatile("s_waitcnt vmcnt(0)" ::: "memory");
    __builtin_amdgcn_s_barrier();
    asm volatile("" ::: "memory");

    f32x4 accs[4] = {};
    #pragma unroll
    for (int j = 0; j < 4; ++j) {
      #pragma unroll
      for (int k4 = 0; k4 < 4; ++k4) {
        int row = j * 16 + fr;
        int ch = (k4 * 4 + g) ^ (row & 7);
        bf16x8 kf = *(const bf16x8*)&lK[row * 128 + ch * 8];
        accs[j] = __builtin_amdgcn_mfma_f32_16x16x32_bf16(kf, af[k4], accs[j], 0, 0, 0);
      }
    }

    float p[16];
    float tmax = NEG;
    #pragma unroll
    for (int j = 0; j < 4; ++j)
      #pragma unroll
      for (int r = 0; r < 4; ++r) {
        float s = accs[j][r];
        int kloc = j * 16 + 4 * g + r;
        bool valid = (kt < qt) || (kloc <= w * 16 + fr);
        s = valid ? s : NEG;
        p[j * 4 + r] = s;
        tmax = fmaxf(tmax, s);
      }
    tmax = fmaxf(tmax, __shfl_xor(tmax, 16));
    tmax = fmaxf(tmax, __shfl_xor(tmax, 32));
    float mnew = fmaxf(mrow, tmax);
    float scale = __expf(mrow - mnew);
    float tsum = 0.f;
    #pragma unroll
    for (int i = 0; i < 16; ++i) { p[i] = __expf(p[i] - mnew); tsum += p[i]; }
    tsum += __shfl_xor(tsum, 16);
    tsum += __shfl_xor(tsum, 32);
    lrow = lrow * scale + tsum;
    mrow = mnew;

    #pragma unroll
    for (int j = 0; j < 4; ++j)
      #pragma unroll
      for (int t = 0; t < 2; ++t) {
        uint32_t u = (uint32_t)f2b(p[j * 4 + 2 * t]) |
                     ((uint32_t)f2b(p[j * 4 + 2 * t + 1]) << 16);
        int kp = 8 * j + 2 * g + t;
        int ch = kp >> 2, wi = kp & 3;
        ((uint32_t*)lP[w])[fr * 32 + ((ch ^ (fr & 7)) << 2) + wi] = u;
      }

    float sc_q[4];
    #pragma unroll
    for (int r = 0; r < 4; ++r) sc_q[r] = __shfl(scale, 4 * g + r);
    #pragma unroll
    for (int j2 = 0; j2 < 4; ++j2)
      #pragma unroll
      for (int r = 0; r < 4; ++r) acc_o[j2][r] *= sc_q[r];

    #pragma unroll
    for (int ksub = 0; ksub < 2; ++ksub) {
      int chp = (4 * ksub + g) ^ (fr & 7);
      bf16x8 pa = *(const bf16x8*)&((const u16*)lP[w])[fr * 64 + chp * 8];
      #pragma unroll
      for (int j2 = 0; j2 < 4; ++j2) {
        int d = j2 * 16 + fr;
        int chv = (ksub * 4 + g) ^ (d & 7);
        bf16x8 vf = *(const bf16x8*)&lV[d * 64 + chv * 8];
        acc_o[j2] = __builtin_amdgcn_mfma_f32_16x16x32_bf16(pa, vf, acc_o[j2], 0, 0, 0);
      }
    }
    asm volatile("" ::: "memory");
    __builtin_amdgcn_s_barrier();
    asm volatile("" ::: "memory");
  }

  float li[4];
  #pragma unroll
  for (int r = 0; r < 4; ++r) li[r] = 1.f / __shfl(lrow, 4 * g + r);
  #pragma unroll
  for (int j2 = 0; j2 < 4; ++j2)
    #pragma unroll
    for (int r = 0; r < 4; ++r) {
      int q = q0 + w * 16 + 4 * g + r;
      int d = j2 * 16 + fr;
      attn[((size_t)(b * Ss) + q) * Dd + h * 64 + d] = f2b(acc_o[j2][r] * li[r]);
    }
}

// ---------------- 128x256xK GEMM, BK=32, 8 waves, double-buffered LDS with
// prefetch + counted vmcnt (T3-minimum), 2 blocks/CU. Chunk-XOR swizzle.
// MODE 0: f32 C = acc + bias
// MODE 1: silu-fused (pair-interleaved Bt): bf16 gate out [M][2816]
template <int MODE>
__global__ __launch_bounds__(512, 4) void k_gemm256b(
    const u16* __restrict__ A, const u16* __restrict__ Bt,
    const float* __restrict__ bias, void* __restrict__ Cv,
    int N, int K) {
  __shared__ u16 lA[2][128 * 32];
  __shared__ u16 lB[2][256 * 32];
  const int tid = threadIdx.x;
  const int gx = gridDim.x;
  const int nwg = gx * gridDim.y;
  const int f = blockIdx.y * gx + blockIdx.x;
  const int f2 = (f & 7) * (nwg >> 3) + (f >> 3);   // xcd swizzle (nwg % 8 == 0)
  const int bx = f2 % gx, by = f2 / gx;
  const long m0 = (long)bx * 128, n0 = (long)by * 256;
  const int lane = tid & 63, wid = tid >> 6;
  const int wm = (wid >> 2) * 64, wn = (wid & 3) * 64;
  const int fr = lane & 15, l4 = lane >> 4;
  const int sw = (fr >> 1) & 3;

  const int ra = tid >> 2;
  const int ca = ((tid & 3) ^ ((ra >> 1) & 3)) * 8;
  const u16* a0 = A + (m0 + ra) * (long)K + ca;
  const int rb = tid >> 2;
  const int cb0 = ((tid & 3) ^ ((rb >> 1) & 3)) * 8;
  const int cb1 = ((tid & 3) ^ (((rb + 128) >> 1) & 3)) * 8;
  const u16* b0 = Bt + (n0 + rb) * (long)K + cb0;
  const u16* b1 = Bt + (n0 + rb + 128) * (long)K + cb1;

  f32x4 acc[4][4] = {};
  const int NT = K >> 5;

  // prologue: tile 0 -> buf0
  gll16(a0, (u16*)lA[0] + tid * 8);
  gll16(b0, (u16*)lB[0] + tid * 8);
  gll16(b1, (u16*)lB[0] + 4096 + tid * 8);

  for (int j = 0; j < NT; ++j) {
    const int cur = j & 1;
    const int kk1 = (j + 1) << 5;
    if (j + 1 < NT) {   // prefetch next tile into other buffer
      gll16(a0 + kk1, (u16*)lA[cur ^ 1] + tid * 8);
      gll16(b0 + kk1, (u16*)lB[cur ^ 1] + tid * 8);
      gll16(b1 + kk1, (u16*)lB[cur ^ 1] + 4096 + tid * 8);
      VMW(3);           // current tile's 3 loads landed; next 3 stay in flight
    } else {
      VMW(0);
    }
    __builtin_amdgcn_s_barrier();
    asm volatile("" ::: "memory");
    bf16x8 af[4], bfv[4];
    #pragma unroll
    for (int i = 0; i < 4; ++i)
      af[i] = *(const bf16x8*)&lA[cur][(wm + i * 16 + fr) * 32 + ((l4 ^ sw) * 8)];
    #pragma unroll
    for (int jj = 0; jj < 4; ++jj)
      bfv[jj] = *(const bf16x8*)&lB[cur][(wn + jj * 16 + fr) * 32 + ((l4 ^ sw) * 8)];
    #pragma unroll
    for (int i = 0; i < 4; ++i)
      #pragma unroll
      for (int jj = 0; jj < 4; ++jj)
        acc[i][jj] = __builtin_amdgcn_mfma_f32_16x16x32_bf16(af[i], bfv[jj], acc[i][jj], 0, 0, 0);
    asm volatile("" ::: "memory");
    __builtin_amdgcn_s_barrier();   // all waves done reading buf[cur] before overwrite
    asm volatile("" ::: "memory");
  }

  const long r0 = m0 + wm + l4 * 4;
  const long c0 = n0 + wn + fr;
  if (MODE == 0) {
    float* C = (float*)Cv;
    #pragma unroll
    for (int j = 0; j < 4; ++j) {
      long col = c0 + j * 16;
      float bs = bias[col];
      #pragma unroll
      for (int i = 0; i < 4; ++i)
        #pragma unroll
        for (int r = 0; r < 4; ++r)
          C[(r0 + i * 16 + r) * (long)N + col] = acc[i][j][r] + bs;
    }
  } else {
    u16* G = (u16*)Cv;
    #pragma unroll
    for (int j = 0; j < 4; ++j) {
      long col = c0 + j * 16;
      int pcol = (int)((col & 1) ? (col >> 1) + 2816 : (col >> 1));
      float bs = bias[pcol];
      #pragma unroll
      for (int i = 0; i < 4; ++i)
        #pragma unroll
        for (int r = 0; r < 4; ++r) {
          float val = acc[i][j][r] + bs;
          float oth = __shfl_xor(val, 1);
          if (!(col & 1)) {
            float x = oth;
            float gv = val * x * (1.f / (1.f + __expf(-x)));
            G[(r0 + i * 16 + r) * 2816L + (col >> 1)] = f2b(gv);
          }
        }
    }
  }
}

// ---------------- bf16 MFMA GEMM 128xBN (m97 structure)
// MODE 0: f32 C = acc + bias ; MODE 1: f32 C += acc + bias
template <int MODE, int BN, bool SWZ>
__global__ __launch_bounds__(256) void k_gemm(
    const u16* __restrict__ A, const u16* __restrict__ Bt,
    const float* __restrict__ bias, void* __restrict__ C,
    int N, int K, long sA, long sB, long sC) {
  __shared__ u16 lA[128 * 32];
  __shared__ u16 lB[BN * 32];
  const int tid = threadIdx.x;
  const int bz = blockIdx.z;

  int bx, by;
  if (SWZ) {
    int gx = gridDim.x;
    int nwg = gx * gridDim.y;
    int f = blockIdx.y * gx + blockIdx.x;
    int f2 = (f & 7) * (nwg >> 3) + (f >> 3);
    bx = f2 % gx; by = f2 / gx;
  } else {
    bx = blockIdx.x; by = blockIdx.y;
  }
  const long m0 = (long)bx * 128, n0 = (long)by * BN;

  const u16* Az = A + (size_t)bz * sA;
  const u16* Bz = Bt + (size_t)bz * sB;
  const int srow = tid >> 2;
  const int scol = (tid & 3) << 3;
  const u16* a0 = Az + (m0 + srow) * (long)K + scol;
  const u16* b0 = Bz + (n0 + srow) * (long)K + scol;
  const long rstep = 64L * K;

  const int lane = tid & 63, wid = tid >> 6;
  constexpr int WR = (BN == 128) ? 64 : 32;
  constexpr int MI = WR / 16;
  const int wm = (BN == 128) ? (wid >> 1) * 64 : wid * 32;
  const int wn = (BN == 128) ? (wid & 1) * 64 : 0;
  const int fr = lane & 15, kg = (lane >> 4) * 8;

  f32x4 acc[MI][4] = {};

  for (int kk = 0; kk < K; kk += 32) {
    gll16(a0 + kk, lA + tid * 8);
    gll16(a0 + rstep + kk, lA + 2048 + tid * 8);
    gll16(b0 + kk, lB + tid * 8);
    if (BN == 128) gll16(b0 + rstep + kk, lB + 2048 + tid * 8);
    __syncthreads();
    bf16x8 af[MI], bfr[4];
    #pragma unroll
    for (int i = 0; i < MI; i++) af[i] = *(const bf16x8*)&lA[(wm + i * 16 + fr) * 32 + kg];
    #pragma unroll
    for (int j = 0; j < 4; j++) bfr[j] = *(const bf16x8*)&lB[(wn + j * 16 + fr) * 32 + kg];
    #pragma unroll
    for (int i = 0; i < MI; i++)
      #pragma unroll
      for (int j = 0; j < 4; j++)
        acc[i][j] = __builtin_amdgcn_mfma_f32_16x16x32_bf16(af[i], bfr[j], acc[i][j], 0, 0, 0);
    __syncthreads();
  }

  const int rb = wm + ((lane >> 4) << 2);
  const int cb = wn + (lane & 15);
  #pragma unroll
  for (int j = 0; j < 4; j++) {
    long gcol = n0 + cb + j * 16;
    float bs = 0.f;
    if (gcol < N) bs = bias[gcol];
    #pragma unroll
    for (int i = 0; i < MI; i++) {
      #pragma unroll
      for (int r = 0; r < 4; r++) {
        long grow = m0 + rb + i * 16 + r;
        float val = acc[i][j][r];
        if (MODE == 0) {
          if (gcol < N) ((float*)C)[grow * N + gcol] = val + bs;
        } else {
          if (gcol < N) { float* p = (float*)C + grow * N + gcol; *p += val + bs; }
        }
      }
    }
  }
}

extern "C" void kernel_launch(void* const* d_in, const int* in_sizes, int n_in,
                              void* d_out, int out_size, void* d_ws, size_t ws_size,
                              hipStream_t stream) {
  (void)in_sizes; (void)n_in; (void)out_size; (void)ws_size;
  const int*   tokens    = (const int*)  d_in[0];
  const float* embed     = (const float*)d_in[1];
  const float* w_kv_down = (const float*)d_in[2];
  const float* b_kv_down = (const float*)d_in[3];
  const float* w_q_down  = (const float*)d_in[4];
  const float* b_q_down  = (const float*)d_in[5];
  const float* w_kv_up   = (const float*)d_in[6];
  const float* b_kv_up   = (const float*)d_in[7];
  const float* w_q_up    = (const float*)d_in[8];
  const float* b_q_up    = (const float*)d_in[9];
  const float* w_o       = (const float*)d_in[10];
  const float* b_o       = (const float*)d_in[11];
  const float* kv_norm_w = (const float*)d_in[12];
  const float* q_norm_w  = (const float*)d_in[13];
  const float* norm1_w   = (const float*)d_in[14];
  const float* norm2_w   = (const float*)d_in[15];
  const float* w_in      = (const float*)d_in[16];
  const float* b_in      = (const float*)d_in[17];
  const float* w_out     = (const float*)d_in[18];
  const float* b_out     = (const float*)d_in[19];
  const float* norm_f_w  = (const float*)d_in[20];
  const float* w_head    = (const float*)d_in[21];
  const float* b_head    = (const float*)d_in[22];

  char* base = (char*)d_ws;
  size_t off = 0;
  auto alloc = [&](size_t bytes) -> void* {
    void* p = base + off;
    off += (bytes + 255) & ~(size_t)255;
    return p;
  };
  u16* warena = (u16*)alloc((size_t)32000 * 1024 * 2);
  u16* wT_dq    = warena;                        // 768 x 1024
  u16* wT_kvup  = wT_dq   + 768 * 1024;          // 2048 x 256
  u16* wT_qup   = wT_kvup + 2048 * 256;          // 1536 x 384
  u16* wT_o     = wT_qup  + 1536 * 384;          // 1024 x 1024
  u16* wT_in    = wT_o    + 1024 * 1024;         // 5632 x 1024 (pair-interleaved)
  u16* wT_out   = wT_in   + 5632 * 1024;         // 1024 x 2816

  float* h     = (float*)alloc((size_t)Mm * 1024 * 4);
  u16*   xn    = (u16*)  alloc((size_t)Mm * 1024 * 2);
  float* ckvq  = (float*)alloc((size_t)Mm * 768 * 4);
  float* bdq   = (float*)alloc(768 * 4);
  u16*   ckvn  = (u16*)  alloc((size_t)Mm * 256 * 2);
  float* kv    = (float*)alloc((size_t)Mm * 2048 * 4);
  u16*   qdn   = (u16*)  alloc((size_t)Mm * 384 * 2);
  float* qf    = (float*)alloc((size_t)Mm * 1536 * 4);
  u16*   Qb    = (u16*)  alloc((size_t)32 * 1024 * QKD * 2);
  u16*   Kb    = (u16*)  alloc((size_t)32 * 1024 * QKD * 2);
  u16*   Vt    = (u16*)  alloc((size_t)32 * 64 * 1024 * 2);
  u16*   attn  = (u16*)  alloc((size_t)Mm * 1024 * 2);
  u16*   gate  = (u16*)  alloc((size_t)Mm * 2816 * 2);

  dim3 tb(32, 8);

  k_embed<<<Mm, 256, 0, stream>>>(tokens, embed, h);

  for (int l = 0; l < 4; l++) {
    // one batched conversion launch for all 7 weights of this layer
    WJobs jb;
    jb.j[0] = { w_kv_down + (size_t)l * 1024 * 288,  wT_dq,              1024, 288,  0, 96 };
    jb.j[1] = { w_q_down  + (size_t)l * 1024 * 384,  wT_dq + 384 * 1024, 1024, 384,  0, 96 };
    jb.j[2] = { w_kv_up   + (size_t)l * 256 * 2048,  wT_kvup,            256,  2048, 0, 128 };
    jb.j[3] = { w_q_up    + (size_t)l * 384 * 1536,  wT_qup,             384,  1536, 0, 144 };
    jb.j[4] = { w_o       + (size_t)l * 1024 * 1024, wT_o,               1024, 1024, 0, 256 };
    jb.j[5] = { w_in      + (size_t)l * 1024 * 5632, wT_in,              1024, 5632, 1, 1408 };
    jb.j[6] = { w_out     + (size_t)l * 2816 * 1024, wT_out,             2816, 1024, 0, 704 };
    k_wcvt_batch<<<2832, 256, 0, stream>>>(jb, 7);
    k_biascat<<<3, 256, 0, stream>>>(b_kv_down + l * 288, b_q_down + l * 384, bdq);

    k_rms<<<Mm, 256, 0, stream>>>(h, 1024, norm1_w + l * 1024, xn, 1024);
    k_gemm<0, 64, true><<<dim3(16, 12), 256, 0, stream>>>(xn, wT_dq, bdq,
                                                          ckvq, 768, 1024, 0, 0, 0);
    k_rms<<<Mm, 256, 0, stream>>>(ckvq, 768, kv_norm_w + l * 256, ckvn, 256);
    k_gemm<0, 128, true><<<dim3(16, 16), 256, 0, stream>>>(ckvn, wT_kvup, b_kv_up + l * 2048,
                                                           kv, 2048, 256, 0, 0, 0);
    k_rms<<<Mm, 256, 0, stream>>>(ckvq + 384, 768, q_norm_w + l * 384, qdn, 384);
    k_gemm<0, 128, true><<<dim3(16, 12), 256, 0, stream>>>(qdn, wT_qup, b_q_up + l * 1536,
                                                           qf, 1536, 384, 0, 0, 0);
    k_buildqk<<<dim3(Ss, 32), 128, 0, stream>>>(qf, kv, ckvq, Qb, Kb);
    k_buildvt<<<dim3(32, 32, 2), tb, 0, stream>>>(kv, Vt);
    k_flash<<<dim3(16, 32), 256, 0, stream>>>(Qb, Kb, Vt, attn);
    k_gemm<1, 64, true><<<dim3(16, 16), 256, 0, stream>>>(attn, wT_o, b_o + l * 1024,
                                                          h, 1024, 1024, 0, 0, 0);
    k_rms<<<Mm, 256, 0, stream>>>(h, 1024, norm2_w + l * 1024, xn, 1024);
    // fused w_in + silu: 128x256 tile, grid 16 x 22 = 352 blocks
    k_gemm256b<1><<<dim3(16, 22), 512, 0, stream>>>(xn, wT_in, b_in + l * 5632,
                                                    gate, 5632, 1024);
    k_gemm<1, 64, true><<<dim3(16, 16), 256, 0, stream>>>(gate, wT_out, b_out + l * 1024,
                                                          h, 1024, 2816, 0, 0, 0);
  }

  k_rms<<<Mm, 256, 0, stream>>>(h, 1024, norm_f_w, xn, 1024);
  {
    WJobs jbh;
    jbh.j[0] = { w_head, warena, 1024, 32000, 0, 8000 };
    k_wcvt_batch<<<8000, 256, 0, stream>>>(jbh, 1);
  }
  // head: 128x256 tile, grid 16 x 125 = 2000 blocks
  k_gemm256b<0><<<dim3(16, 125), 512, 0, stream>>>(xn, warena, b_head,
                                                   (float*)d_out, 32000, 1024);
}